// Round 1
// baseline (894.006 us; speedup 1.0000x reference)
//
#include <hip/hip_runtime.h>

// Problem constants (match reference)
constexpr int N_USERS  = 100000;
constexpr int N_MOVIES = 50000;
constexpr int N_NODES  = N_USERS + N_MOVIES;   // 150000
constexpr int N_EDGES  = 1000000;
constexpr int IN_CH = 64, HID = 128, OUT_CH = 64;

// ---------------------------------------------------------------------------
// Scatter layer 1: msg[dst] += x[src] (64 ch), deg[dst] += 1
// One wave per edge, lane = channel. x = concat(user_emb, movie_emb) read
// directly from the two source buffers (no materialized concat).
// ---------------------------------------------------------------------------
__global__ __launch_bounds__(256) void scatter_x(const int* __restrict__ ei,
                                                 const float* __restrict__ ue,
                                                 const float* __restrict__ me,
                                                 float* __restrict__ msg,
                                                 float* __restrict__ deg) {
    int gid = blockIdx.x * 256 + threadIdx.x;
    int e   = gid >> 6;
    int ch  = gid & 63;
    if (e >= N_EDGES) return;
    int src = ei[e];
    int dst = ei[N_EDGES + e];
    float v = (src < N_USERS) ? ue[src * 64 + ch]
                              : me[(src - N_USERS) * 64 + ch];
    atomicAdd(&msg[dst * 64 + ch], v);
    if (ch == 0) atomicAdd(&deg[dst], 1.0f);
}

// ---------------------------------------------------------------------------
// Scatter layer 2: msg[dst] += z[src]  (z = h1 @ W2l.T, 64 ch)
// ---------------------------------------------------------------------------
__global__ __launch_bounds__(256) void scatter_z(const int* __restrict__ ei,
                                                 const float* __restrict__ z,
                                                 float* __restrict__ msg) {
    int gid = blockIdx.x * 256 + threadIdx.x;
    int e   = gid >> 6;
    int ch  = gid & 63;
    if (e >= N_EDGES) return;
    int src = ei[e];
    int dst = ei[N_EDGES + e];
    atomicAdd(&msg[dst * 64 + ch], z[src * 64 + ch]);
}

// ---------------------------------------------------------------------------
// Dense layer 1: h1[n,:] = relu( (msg[n,:]/max(deg,1)) @ W1l.T + b1 + x[n,:] @ W1r.T )
// Block: 32 nodes x 128 och, 256 threads, each thread 4 och x 4 nodes.
// Weights + inputs staged transposed in LDS (padded rows, 16B-aligned).
// ---------------------------------------------------------------------------
__global__ __launch_bounds__(256) void dense1(const float* __restrict__ msg,
                                              const float* __restrict__ deg,
                                              const float* __restrict__ ue,
                                              const float* __restrict__ me,
                                              const float* __restrict__ W1l,
                                              const float* __restrict__ b1,
                                              const float* __restrict__ W1r,
                                              float* __restrict__ h1) {
    __shared__ float WlT[64][132];   // [k][o], pad 128+4 (rows 528B, 16B aligned)
    __shared__ float WrT[64][132];
    __shared__ float aggT[64][36];   // [k][n], pad 32+4 (rows 144B, 16B aligned)
    __shared__ float xT[64][36];

    const int tid = threadIdx.x;
    // Stage weights transposed: W1l is [128][64] row-major (o,k)
    for (int i = tid; i < 128 * 64; i += 256) {
        int o = i >> 6, k = i & 63;
        WlT[k][o] = W1l[i];
        WrT[k][o] = W1r[i];
    }
    const int node0 = blockIdx.x * 32;
    // Stage inputs transposed (coalesced global reads)
    for (int i = tid; i < 32 * 64; i += 256) {
        int n = i >> 6, k = i & 63;
        int node = node0 + n;
        float a = 0.f, xv = 0.f;
        if (node < N_NODES) {
            float d = fmaxf(deg[node], 1.0f);
            a  = msg[node * 64 + k] / d;
            xv = (node < N_USERS) ? ue[node * 64 + k]
                                  : me[(node - N_USERS) * 64 + k];
        }
        aggT[k][n] = a;
        xT[k][n]   = xv;
    }
    __syncthreads();

    const int og = (tid & 31) * 4;   // 32 groups x 4 = 128 och
    const int ng = (tid >> 5) * 4;   // 8 groups x 4 = 32 nodes
    float acc[4][4] = {};
#pragma unroll 8
    for (int k = 0; k < 64; ++k) {
        float4 wl4 = *(const float4*)&WlT[k][og];
        float4 wr4 = *(const float4*)&WrT[k][og];
        float4 a4  = *(const float4*)&aggT[k][ng];
        float4 x4  = *(const float4*)&xT[k][ng];
        float wl[4] = {wl4.x, wl4.y, wl4.z, wl4.w};
        float wr[4] = {wr4.x, wr4.y, wr4.z, wr4.w};
        float aa[4] = {a4.x, a4.y, a4.z, a4.w};
        float xx[4] = {x4.x, x4.y, x4.z, x4.w};
#pragma unroll
        for (int n = 0; n < 4; ++n)
#pragma unroll
            for (int o = 0; o < 4; ++o)
                acc[n][o] += aa[n] * wl[o] + xx[n] * wr[o];
    }

    float bb[4] = {b1[og], b1[og + 1], b1[og + 2], b1[og + 3]};
#pragma unroll
    for (int n = 0; n < 4; ++n) {
        int node = node0 + ng + n;
        if (node < N_NODES) {
            float4 r;
            r.x = fmaxf(acc[n][0] + bb[0], 0.f);
            r.y = fmaxf(acc[n][1] + bb[1], 0.f);
            r.z = fmaxf(acc[n][2] + bb[2], 0.f);
            r.w = fmaxf(acc[n][3] + bb[3], 0.f);
            *(float4*)&h1[node * 128 + og] = r;
        }
    }
}

// ---------------------------------------------------------------------------
// Layer-2 transform (linearity trick): z[n,:] = h1[n,:] @ W2l.T   (128 -> 64)
// Block: 64 nodes x 64 och, 256 threads, each 4 och x 4 nodes.
// ---------------------------------------------------------------------------
__global__ __launch_bounds__(256) void transform2(const float* __restrict__ h1,
                                                  const float* __restrict__ W2l,
                                                  float* __restrict__ z) {
    __shared__ float WT[128][68];   // [k][o], pad 64+4 (rows 272B, 16B aligned)
    __shared__ float hT[128][68];   // [k][n]

    const int tid = threadIdx.x;
    for (int i = tid; i < 64 * 128; i += 256) {   // W2l is [64][128] (o,k)
        int o = i >> 7, k = i & 127;
        WT[k][o] = W2l[i];
    }
    const int node0 = blockIdx.x * 64;
    for (int i = tid; i < 64 * 128; i += 256) {
        int n = i >> 7, k = i & 127;
        int node = node0 + n;
        hT[k][n] = (node < N_NODES) ? h1[node * 128 + k] : 0.f;
    }
    __syncthreads();

    const int og = (tid & 15) * 4;   // 16 groups x 4 = 64 och
    const int ng = (tid >> 4) * 4;   // 16 groups x 4 = 64 nodes
    float acc[4][4] = {};
#pragma unroll 8
    for (int k = 0; k < 128; ++k) {
        float4 w4 = *(const float4*)&WT[k][og];
        float4 h4 = *(const float4*)&hT[k][ng];
        float ww[4] = {w4.x, w4.y, w4.z, w4.w};
        float hh[4] = {h4.x, h4.y, h4.z, h4.w};
#pragma unroll
        for (int n = 0; n < 4; ++n)
#pragma unroll
            for (int o = 0; o < 4; ++o)
                acc[n][o] += hh[n] * ww[o];
    }
#pragma unroll
    for (int n = 0; n < 4; ++n) {
        int node = node0 + ng + n;
        if (node < N_NODES) {
            float4 r = {acc[n][0], acc[n][1], acc[n][2], acc[n][3]};
            *(float4*)&z[node * 64 + og] = r;
        }
    }
}

// ---------------------------------------------------------------------------
// Final dense: out[n,:] = msg2[n,:]/max(deg,1) + b2 + h1[n,:] @ W2r.T
// ---------------------------------------------------------------------------
__global__ __launch_bounds__(256) void dense2_final(const float* __restrict__ msg,
                                                    const float* __restrict__ deg,
                                                    const float* __restrict__ h1,
                                                    const float* __restrict__ W2r,
                                                    const float* __restrict__ b2,
                                                    float* __restrict__ out) {
    __shared__ float WT[128][68];
    __shared__ float hT[128][68];

    const int tid = threadIdx.x;
    for (int i = tid; i < 64 * 128; i += 256) {   // W2r is [64][128] (o,k)
        int o = i >> 7, k = i & 127;
        WT[k][o] = W2r[i];
    }
    const int node0 = blockIdx.x * 64;
    for (int i = tid; i < 64 * 128; i += 256) {
        int n = i >> 7, k = i & 127;
        int node = node0 + n;
        hT[k][n] = (node < N_NODES) ? h1[node * 128 + k] : 0.f;
    }
    __syncthreads();

    const int og = (tid & 15) * 4;
    const int ng = (tid >> 4) * 4;
    float acc[4][4] = {};
#pragma unroll 8
    for (int k = 0; k < 128; ++k) {
        float4 w4 = *(const float4*)&WT[k][og];
        float4 h4 = *(const float4*)&hT[k][ng];
        float ww[4] = {w4.x, w4.y, w4.z, w4.w};
        float hh[4] = {h4.x, h4.y, h4.z, h4.w};
#pragma unroll
        for (int n = 0; n < 4; ++n)
#pragma unroll
            for (int o = 0; o < 4; ++o)
                acc[n][o] += hh[n] * ww[o];
    }

    float bb[4] = {b2[og], b2[og + 1], b2[og + 2], b2[og + 3]};
#pragma unroll
    for (int n = 0; n < 4; ++n) {
        int node = node0 + ng + n;
        if (node < N_NODES) {
            float d = fmaxf(deg[node], 1.0f);
            float4 m4 = *(const float4*)&msg[node * 64 + og];
            float4 r;
            r.x = acc[n][0] + m4.x / d + bb[0];
            r.y = acc[n][1] + m4.y / d + bb[1];
            r.z = acc[n][2] + m4.z / d + bb[2];
            r.w = acc[n][3] + m4.w / d + bb[3];
            *(float4*)&out[node * 64 + og] = r;
        }
    }
}

// ---------------------------------------------------------------------------
// Launch
// ---------------------------------------------------------------------------
extern "C" void kernel_launch(void* const* d_in, const int* in_sizes, int n_in,
                              void* d_out, int out_size, void* d_ws, size_t ws_size,
                              hipStream_t stream) {
    const int*   ei  = (const int*)d_in[0];     // [2, 1M]
    const float* ue  = (const float*)d_in[1];   // [100000, 64]
    const float* me  = (const float*)d_in[2];   // [50000, 64]
    const float* W1l = (const float*)d_in[3];   // [128, 64]
    const float* b1  = (const float*)d_in[4];   // [128]
    const float* W1r = (const float*)d_in[5];   // [128, 64]
    const float* W2l = (const float*)d_in[6];   // [64, 128]
    const float* b2  = (const float*)d_in[7];   // [64]
    const float* W2r = (const float*)d_in[8];   // [64, 128]
    float* out = (float*)d_out;                 // [150000, 64]

    // Workspace layout (floats): msg [150000*64] | deg [150000] | h1 [150000*128]
    float* msg = (float*)d_ws;
    float* deg = msg + (size_t)N_NODES * 64;
    float* h1  = deg + N_NODES;

    // Zero msg + deg (contiguous)
    hipMemsetAsync(msg, 0, ((size_t)N_NODES * 64 + N_NODES) * sizeof(float), stream);

    // Layer 1: aggregate x, then dense
    {
        int total = N_EDGES * 64;
        scatter_x<<<total / 256, 256, 0, stream>>>(ei, ue, me, msg, deg);
        int blocks = (N_NODES + 31) / 32;
        dense1<<<blocks, 256, 0, stream>>>(msg, deg, ue, me, W1l, b1, W1r, h1);
    }

    // Layer 2: transform-first (z = h1 @ W2l.T into d_out), aggregate z, final dense
    {
        int blocks = (N_NODES + 63) / 64;
        transform2<<<blocks, 256, 0, stream>>>(h1, W2l, out);
        hipMemsetAsync(msg, 0, (size_t)N_NODES * 64 * sizeof(float), stream);
        int total = N_EDGES * 64;
        scatter_z<<<total / 256, 256, 0, stream>>>(ei, out, msg);
        dense2_final<<<blocks, 256, 0, stream>>>(msg, deg, h1, W2r, b2, out);
    }
}

// Round 2
// 589.576 us; speedup vs baseline: 1.5164x; 1.5164x over previous
//
#include <hip/hip_runtime.h>

constexpr int N_USERS  = 100000;
constexpr int N_MOVIES = 50000;
constexpr int N_NODES  = N_USERS + N_MOVIES;   // 150000
constexpr int N_EDGES  = 1000000;

// ---------------------------------------------------------------------------
// CSR build: count -> scan(3 kernels) -> fill
// ---------------------------------------------------------------------------
__global__ __launch_bounds__(256) void csr_count(const int* __restrict__ ei,
                                                 int* __restrict__ cnt) {
    int e = blockIdx.x * 256 + threadIdx.x;
    if (e < N_EDGES) atomicAdd(&cnt[ei[N_EDGES + e]], 1);
}

// 1024 elems/block (256 thr x 4), exclusive scan partials + block sums
__global__ __launch_bounds__(256) void scan1(const int* __restrict__ cnt,
                                             int* __restrict__ part,
                                             int* __restrict__ bsum) {
    __shared__ int sh[256];
    int t = threadIdx.x, b = blockIdx.x;
    int base = b * 1024 + t * 4;
    int v[4]; int s = 0;
#pragma unroll
    for (int j = 0; j < 4; ++j) {
        int i = base + j;
        v[j] = (i < N_NODES) ? cnt[i] : 0;
        s += v[j];
    }
    sh[t] = s; __syncthreads();
    for (int off = 1; off < 256; off <<= 1) {
        int x = (t >= off) ? sh[t - off] : 0;
        __syncthreads();
        sh[t] += x;
        __syncthreads();
    }
    int run = sh[t] - s;   // exclusive prefix for this thread
#pragma unroll
    for (int j = 0; j < 4; ++j) {
        int i = base + j;
        if (i < N_NODES) part[i] = run;
        run += v[j];
    }
    if (t == 255) bsum[b] = sh[255];
}

__global__ __launch_bounds__(256) void scan2(int* __restrict__ bsum, int nb) {
    __shared__ int sh[256];
    int t = threadIdx.x;
    int v = (t < nb) ? bsum[t] : 0;
    sh[t] = v; __syncthreads();
    for (int off = 1; off < 256; off <<= 1) {
        int x = (t >= off) ? sh[t - off] : 0;
        __syncthreads();
        sh[t] += x;
        __syncthreads();
    }
    if (t < nb) bsum[t] = sh[t] - v;   // exclusive
}

__global__ __launch_bounds__(256) void scan3(int* __restrict__ row_ptr,
                                             const int* __restrict__ bsum,
                                             int* __restrict__ fill) {
    int t = threadIdx.x, b = blockIdx.x;
    int base = b * 1024 + t * 4;
    int add = bsum[b];
#pragma unroll
    for (int j = 0; j < 4; ++j) {
        int i = base + j;
        if (i < N_NODES) {
            int r = row_ptr[i] + add;
            row_ptr[i] = r;
            fill[i] = r;
        }
    }
    if (b == 0 && t == 0) row_ptr[N_NODES] = N_EDGES;
}

__global__ __launch_bounds__(256) void csr_fill(const int* __restrict__ ei,
                                                int* __restrict__ fill,
                                                int* __restrict__ srclist) {
    int e = blockIdx.x * 256 + threadIdx.x;
    if (e < N_EDGES) {
        int dst = ei[N_EDGES + e];
        int pos = atomicAdd(&fill[dst], 1);
        srclist[pos] = ei[e];
    }
}

// ---------------------------------------------------------------------------
// Gather-mean: one wave per node, lane = channel. No atomics.
// SPLIT: features come from two concatenated buffers (user/movie).
// Writes agg[node*stride + off + lane].
// ---------------------------------------------------------------------------
template <bool SPLIT>
__global__ __launch_bounds__(256) void gather_mean(const int* __restrict__ row_ptr,
                                                   const int* __restrict__ srclist,
                                                   const float* __restrict__ fa,
                                                   const float* __restrict__ fb,
                                                   float* __restrict__ agg,
                                                   int stride, int off) {
    int w    = (blockIdx.x * 256 + threadIdx.x) >> 6;
    int lane = threadIdx.x & 63;
    if (w >= N_NODES) return;
    int s0 = row_ptr[w], s1 = row_ptr[w + 1];
    float acc = 0.f;
    int i = s0;
    for (; i + 1 < s1; i += 2) {
        int a = srclist[i], b = srclist[i + 1];
        const float* pa = SPLIT ? (a < N_USERS ? fa + (size_t)a * 64
                                               : fb + (size_t)(a - N_USERS) * 64)
                                : fa + (size_t)a * 64;
        const float* pb = SPLIT ? (b < N_USERS ? fa + (size_t)b * 64
                                               : fb + (size_t)(b - N_USERS) * 64)
                                : fa + (size_t)b * 64;
        float v0 = pa[lane], v1 = pb[lane];
        acc += v0;
        acc += v1;
    }
    if (i < s1) {
        int a = srclist[i];
        const float* pa = SPLIT ? (a < N_USERS ? fa + (size_t)a * 64
                                               : fb + (size_t)(a - N_USERS) * 64)
                                : fa + (size_t)a * 64;
        acc += pa[lane];
    }
    float d = fmaxf((float)(s1 - s0), 1.0f);
    agg[(size_t)w * stride + off + lane] = acc / d;
}

// ---------------------------------------------------------------------------
// Dense layer 1: h1[n,:] = relu( agg1[n,:] @ W1l.T + b1 + x[n,:] @ W1r.T )
// agg1 already mean-divided. Block: 32 nodes x 128 och.
// ---------------------------------------------------------------------------
__global__ __launch_bounds__(256) void dense1(const float* __restrict__ agg1,
                                              const float* __restrict__ ue,
                                              const float* __restrict__ me,
                                              const float* __restrict__ W1l,
                                              const float* __restrict__ b1,
                                              const float* __restrict__ W1r,
                                              float* __restrict__ h1) {
    __shared__ float WlT[64][132];
    __shared__ float WrT[64][132];
    __shared__ float aggT[64][36];
    __shared__ float xT[64][36];

    const int tid = threadIdx.x;
    for (int i = tid; i < 128 * 64; i += 256) {   // W1l/W1r are [128][64] (o,k)
        int o = i >> 6, k = i & 63;
        WlT[k][o] = W1l[i];
        WrT[k][o] = W1r[i];
    }
    const int node0 = blockIdx.x * 32;
    for (int i = tid; i < 32 * 64; i += 256) {
        int n = i >> 6, k = i & 63;
        int node = node0 + n;
        float a = 0.f, xv = 0.f;
        if (node < N_NODES) {
            a  = agg1[(size_t)node * 64 + k];
            xv = (node < N_USERS) ? ue[(size_t)node * 64 + k]
                                  : me[(size_t)(node - N_USERS) * 64 + k];
        }
        aggT[k][n] = a;
        xT[k][n]   = xv;
    }
    __syncthreads();

    const int og = (tid & 31) * 4;
    const int ng = (tid >> 5) * 4;
    float acc[4][4] = {};
#pragma unroll 8
    for (int k = 0; k < 64; ++k) {
        float4 wl4 = *(const float4*)&WlT[k][og];
        float4 wr4 = *(const float4*)&WrT[k][og];
        float4 a4  = *(const float4*)&aggT[k][ng];
        float4 x4  = *(const float4*)&xT[k][ng];
        float wl[4] = {wl4.x, wl4.y, wl4.z, wl4.w};
        float wr[4] = {wr4.x, wr4.y, wr4.z, wr4.w};
        float aa[4] = {a4.x, a4.y, a4.z, a4.w};
        float xx[4] = {x4.x, x4.y, x4.z, x4.w};
#pragma unroll
        for (int n = 0; n < 4; ++n)
#pragma unroll
            for (int o = 0; o < 4; ++o)
                acc[n][o] += aa[n] * wl[o] + xx[n] * wr[o];
    }

    float bb[4] = {b1[og], b1[og + 1], b1[og + 2], b1[og + 3]};
#pragma unroll
    for (int n = 0; n < 4; ++n) {
        int node = node0 + ng + n;
        if (node < N_NODES) {
            float4 r;
            r.x = fmaxf(acc[n][0] + bb[0], 0.f);
            r.y = fmaxf(acc[n][1] + bb[1], 0.f);
            r.z = fmaxf(acc[n][2] + bb[2], 0.f);
            r.w = fmaxf(acc[n][3] + bb[3], 0.f);
            *(float4*)&h1[(size_t)node * 128 + og] = r;
        }
    }
}

// ---------------------------------------------------------------------------
// transform2b: z = h1 @ W2l.T -> z_out; w = h1 @ W2r.T -> in-place into
// B[node*128 + 0..64) (own rows only; hT staged in LDS before any write).
// Block: 64 nodes. LDS reused between the two matmuls (re-stage weights).
// ---------------------------------------------------------------------------
__global__ __launch_bounds__(256) void transform2b(float* __restrict__ B,
                                                   const float* __restrict__ W2l,
                                                   const float* __restrict__ W2r,
                                                   float* __restrict__ z) {
    __shared__ float WT[128][68];
    __shared__ float hT[128][68];

    const int tid = threadIdx.x;
    const int node0 = blockIdx.x * 64;
    for (int i = tid; i < 64 * 128; i += 256) {
        int n = i >> 7, k = i & 127;
        int node = node0 + n;
        hT[k][n] = (node < N_NODES) ? B[(size_t)node * 128 + k] : 0.f;
    }
    for (int i = tid; i < 64 * 128; i += 256) {   // W2l is [64][128] (o,k)
        int o = i >> 7, k = i & 127;
        WT[k][o] = W2l[i];
    }
    __syncthreads();

    const int og = (tid & 15) * 4;
    const int ng = (tid >> 4) * 4;
    {
        float acc[4][4] = {};
#pragma unroll 8
        for (int k = 0; k < 128; ++k) {
            float4 w4 = *(const float4*)&WT[k][og];
            float4 h4 = *(const float4*)&hT[k][ng];
            float ww[4] = {w4.x, w4.y, w4.z, w4.w};
            float hh[4] = {h4.x, h4.y, h4.z, h4.w};
#pragma unroll
            for (int n = 0; n < 4; ++n)
#pragma unroll
                for (int o = 0; o < 4; ++o)
                    acc[n][o] += hh[n] * ww[o];
        }
#pragma unroll
        for (int n = 0; n < 4; ++n) {
            int node = node0 + ng + n;
            if (node < N_NODES) {
                float4 r = {acc[n][0], acc[n][1], acc[n][2], acc[n][3]};
                *(float4*)&z[(size_t)node * 64 + og] = r;
            }
        }
    }
    __syncthreads();
    for (int i = tid; i < 64 * 128; i += 256) {   // re-stage with W2r
        int o = i >> 7, k = i & 127;
        WT[k][o] = W2r[i];
    }
    __syncthreads();
    {
        float acc[4][4] = {};
#pragma unroll 8
        for (int k = 0; k < 128; ++k) {
            float4 w4 = *(const float4*)&WT[k][og];
            float4 h4 = *(const float4*)&hT[k][ng];
            float ww[4] = {w4.x, w4.y, w4.z, w4.w};
            float hh[4] = {h4.x, h4.y, h4.z, h4.w};
#pragma unroll
            for (int n = 0; n < 4; ++n)
#pragma unroll
                for (int o = 0; o < 4; ++o)
                    acc[n][o] += hh[n] * ww[o];
        }
#pragma unroll
        for (int n = 0; n < 4; ++n) {
            int node = node0 + ng + n;
            if (node < N_NODES) {
                float4 r = {acc[n][0], acc[n][1], acc[n][2], acc[n][3]};
                *(float4*)&B[(size_t)node * 128 + og] = r;   // og < 64
            }
        }
    }
}

// ---------------------------------------------------------------------------
// final: out[n,o] = w[n,o] + agg2[n,o] + b2[o]
// w at B[n*128 + o], agg2 at B[n*128 + 64 + o] -> contiguous 128-f row read.
// ---------------------------------------------------------------------------
__global__ __launch_bounds__(256) void final_add(const float* __restrict__ B,
                                                 const float* __restrict__ b2,
                                                 float* __restrict__ out) {
    int gid = blockIdx.x * 256 + threadIdx.x;   // over N_NODES*16 float4s
    if (gid >= N_NODES * 16) return;
    int n = gid >> 4, q = gid & 15;
    float4 w = *(const float4*)&B[(size_t)n * 128 + q * 4];
    float4 a = *(const float4*)&B[(size_t)n * 128 + 64 + q * 4];
    float4 bb = *(const float4*)&b2[q * 4];
    float4 r;
    r.x = w.x + a.x + bb.x;
    r.y = w.y + a.y + bb.y;
    r.z = w.z + a.z + bb.z;
    r.w = w.w + a.w + bb.w;
    *(float4*)&out[(size_t)n * 64 + q * 4] = r;
}

// ---------------------------------------------------------------------------
// Launch
// ---------------------------------------------------------------------------
extern "C" void kernel_launch(void* const* d_in, const int* in_sizes, int n_in,
                              void* d_out, int out_size, void* d_ws, size_t ws_size,
                              hipStream_t stream) {
    const int*   ei  = (const int*)d_in[0];
    const float* ue  = (const float*)d_in[1];
    const float* me  = (const float*)d_in[2];
    const float* W1l = (const float*)d_in[3];
    const float* b1  = (const float*)d_in[4];
    const float* W1r = (const float*)d_in[5];
    const float* W2l = (const float*)d_in[6];
    const float* b2  = (const float*)d_in[7];
    const float* W2r = (const float*)d_in[8];
    float* out = (float*)d_out;

    // ws layout: row_ptr[N+1] | srclist[1M] | B[150000*128]
    // cnt/fill + bsum overlaid on the head of B during CSR build (B unused then).
    char* p = (char*)d_ws;
    int* row_ptr = (int*)p;                      p += ((N_NODES + 1) * 4 + 255) / 256 * 256;
    int* srclist = (int*)p;                      p += (size_t)N_EDGES * 4;
    float* B     = (float*)p;                    // 150000*128 floats (76.8 MB)
    int* cnt  = (int*)B;                          // overlay (dead before dense1)
    int* bsum = cnt + N_NODES;                    // 256 ints

    const int NB = (N_NODES + 1023) / 1024;       // 147 scan blocks

    // --- CSR build ---
    hipMemsetAsync(cnt, 0, N_NODES * sizeof(int), stream);
    csr_count<<<(N_EDGES + 255) / 256, 256, 0, stream>>>(ei, cnt);
    scan1<<<NB, 256, 0, stream>>>(cnt, row_ptr, bsum);
    scan2<<<1, 256, 0, stream>>>(bsum, NB);
    scan3<<<NB, 256, 0, stream>>>(row_ptr, bsum, cnt /*fill*/);
    csr_fill<<<(N_EDGES + 255) / 256, 256, 0, stream>>>(ei, cnt /*fill*/, srclist);

    // --- Layer 1: gather-mean x -> agg1 (staged in d_out), dense ---
    {
        int blocks = (N_NODES * 64 + 255) / 256;
        gather_mean<true><<<blocks, 256, 0, stream>>>(row_ptr, srclist, ue, me,
                                                      out /*agg1*/, 64, 0);
        dense1<<<(N_NODES + 31) / 32, 256, 0, stream>>>(out /*agg1*/, ue, me,
                                                        W1l, b1, W1r, B /*h1*/);
    }

    // --- Layer 2: z & w from h1; gather-mean z; final add ---
    {
        transform2b<<<(N_NODES + 63) / 64, 256, 0, stream>>>(B, W2l, W2r, out /*z*/);
        int blocks = (N_NODES * 64 + 255) / 256;
        gather_mean<false><<<blocks, 256, 0, stream>>>(row_ptr, srclist, out /*z*/,
                                                       nullptr, B /*agg2*/, 128, 64);
        final_add<<<(N_NODES * 16 + 255) / 256, 256, 0, stream>>>(B, b2, out);
    }
}

// Round 3
// 491.390 us; speedup vs baseline: 1.8193x; 1.1998x over previous
//
#include <hip/hip_runtime.h>

constexpr int N_USERS  = 100000;
constexpr int N_MOVIES = 50000;
constexpr int N_NODES  = N_USERS + N_MOVIES;   // 150000
constexpr int N_EDGES  = 1000000;

// ---------------------------------------------------------------------------
// CSR build: count -> scan(3 kernels) -> fill
// ---------------------------------------------------------------------------
__global__ __launch_bounds__(256) void csr_count(const int* __restrict__ ei,
                                                 int* __restrict__ cnt) {
    int e = blockIdx.x * 256 + threadIdx.x;
    if (e < N_EDGES) atomicAdd(&cnt[ei[N_EDGES + e]], 1);
}

__global__ __launch_bounds__(256) void scan1(const int* __restrict__ cnt,
                                             int* __restrict__ part,
                                             int* __restrict__ bsum) {
    __shared__ int sh[256];
    int t = threadIdx.x, b = blockIdx.x;
    int base = b * 1024 + t * 4;
    int v[4]; int s = 0;
#pragma unroll
    for (int j = 0; j < 4; ++j) {
        int i = base + j;
        v[j] = (i < N_NODES) ? cnt[i] : 0;
        s += v[j];
    }
    sh[t] = s; __syncthreads();
    for (int off = 1; off < 256; off <<= 1) {
        int x = (t >= off) ? sh[t - off] : 0;
        __syncthreads();
        sh[t] += x;
        __syncthreads();
    }
    int run = sh[t] - s;
#pragma unroll
    for (int j = 0; j < 4; ++j) {
        int i = base + j;
        if (i < N_NODES) part[i] = run;
        run += v[j];
    }
    if (t == 255) bsum[b] = sh[255];
}

__global__ __launch_bounds__(256) void scan2(int* __restrict__ bsum, int nb) {
    __shared__ int sh[256];
    int t = threadIdx.x;
    int v = (t < nb) ? bsum[t] : 0;
    sh[t] = v; __syncthreads();
    for (int off = 1; off < 256; off <<= 1) {
        int x = (t >= off) ? sh[t - off] : 0;
        __syncthreads();
        sh[t] += x;
        __syncthreads();
    }
    if (t < nb) bsum[t] = sh[t] - v;
}

__global__ __launch_bounds__(256) void scan3(int* __restrict__ row_ptr,
                                             const int* __restrict__ bsum,
                                             int* __restrict__ fill) {
    int t = threadIdx.x, b = blockIdx.x;
    int base = b * 1024 + t * 4;
    int add = bsum[b];
#pragma unroll
    for (int j = 0; j < 4; ++j) {
        int i = base + j;
        if (i < N_NODES) {
            int r = row_ptr[i] + add;
            row_ptr[i] = r;
            fill[i] = r;
        }
    }
    if (b == 0 && t == 0) row_ptr[N_NODES] = N_EDGES;
}

__global__ __launch_bounds__(256) void csr_fill(const int* __restrict__ ei,
                                                int* __restrict__ fill,
                                                int* __restrict__ srclist) {
    int e = blockIdx.x * 256 + threadIdx.x;
    if (e < N_EDGES) {
        int dst = ei[N_EDGES + e];
        int pos = atomicAdd(&fill[dst], 1);
        srclist[pos] = ei[e];
    }
}

// ---------------------------------------------------------------------------
// Build pre-transposed weight matrices (k-major) so GEMM staging is a linear
// conflict-free copy.
//   Wt1[k][o] = k<64 ? W1l[o][k] : W1r[o][k-64]     (layer1 K-concat)
//   Wt2[k][o] = o<64 ? W2l[o][k] : W2r[o-64][k]     (layer2 O-concat -> [z|w])
// ---------------------------------------------------------------------------
__global__ __launch_bounds__(256) void build_wt(const float* __restrict__ W1l,
                                                const float* __restrict__ W1r,
                                                const float* __restrict__ W2l,
                                                const float* __restrict__ W2r,
                                                float* __restrict__ Wt1,
                                                float* __restrict__ Wt2) {
    int i = blockIdx.x * 256 + threadIdx.x;
    if (i < 128 * 128) {
        int k = i >> 7, o = i & 127;
        Wt1[i] = (k < 64) ? W1l[o * 64 + k] : W1r[o * 64 + (k - 64)];
        Wt2[i] = (o < 64) ? W2l[o * 128 + k] : W2r[(o - 64) * 128 + k];
    }
}

// ---------------------------------------------------------------------------
// gather1: agg1[n][lane] = mean over neighbors of x[src][lane]
// One wave per node, lane = channel, no atomics.
// ---------------------------------------------------------------------------
__global__ __launch_bounds__(256) void gather1(const int* __restrict__ row_ptr,
                                               const int* __restrict__ srclist,
                                               const float* __restrict__ ue,
                                               const float* __restrict__ me,
                                               float* __restrict__ agg) {
    int w    = (blockIdx.x * 256 + threadIdx.x) >> 6;
    int lane = threadIdx.x & 63;
    if (w >= N_NODES) return;
    int s0 = row_ptr[w], s1 = row_ptr[w + 1];
    float acc = 0.f;
    int i = s0;
    for (; i + 1 < s1; i += 2) {
        int a = srclist[i], b = srclist[i + 1];
        const float* pa = (a < N_USERS) ? ue + (size_t)a * 64 : me + (size_t)(a - N_USERS) * 64;
        const float* pb = (b < N_USERS) ? ue + (size_t)b * 64 : me + (size_t)(b - N_USERS) * 64;
        acc += pa[lane];
        acc += pb[lane];
    }
    if (i < s1) {
        int a = srclist[i];
        const float* pa = (a < N_USERS) ? ue + (size_t)a * 64 : me + (size_t)(a - N_USERS) * 64;
        acc += pa[lane];
    }
    float d = fmaxf((float)(s1 - s0), 1.0f);
    agg[(size_t)w * 64 + lane] = acc / d;
}

// ---------------------------------------------------------------------------
// gemm128: C[n][o] = sum_k A[n][k] * Wt[k][o]  (+bias, relu if LAYER1)
// M-tile 128 nodes, N = 128 och, K = 128 in two 64-chunks.
// 256 threads, 8x8 register tile, och/node indices split {c, c+64} so
// main-loop ds_reads hit 64 consecutive LDS words (2-way / broadcast = free).
// LAYER1: A-row = [agg(64) | x(64)] gathered from agg/ue/me.
// LAYER2: in-place safe (each block reads only the rows it overwrites,
//         all reads precede the epilogue stores) -> Ain/C not restrict.
// ---------------------------------------------------------------------------
template <bool LAYER1>
__global__ __launch_bounds__(256) void gemm128(const float* Ain,
                                               const float* __restrict__ agg,
                                               const float* __restrict__ ue,
                                               const float* __restrict__ me,
                                               const float* __restrict__ Wt,
                                               const float* __restrict__ bias,
                                               float* C) {
    __shared__ float As[64][132];
    __shared__ float Ws[64][132];
    const int tid = threadIdx.x;
    const int n0  = blockIdx.x * 128;
    const int oc  = tid & 15;    // och chunk: cols {oc*4..+3} and {64+oc*4..+3}
    const int nc  = tid >> 4;    // node chunk: rows {nc*4..+3} and {64+nc*4..+3}

    float acc[8][8] = {};        // [node][och]

    for (int kc = 0; kc < 2; ++kc) {
        // Ws: linear copy from pre-transposed Wt (coalesced + conflict-free)
        for (int idx = tid; idx < 64 * 128; idx += 256) {
            int k = idx >> 7, o = idx & 127;
            Ws[k][o] = Wt[(kc * 64 + k) * 128 + o];
        }
        // As: transposed stage (coalesced global, 8-way LDS write conflict ok)
        for (int idx = tid; idx < 128 * 64; idx += 256) {
            int n = idx >> 6, k = idx & 63;
            int node = n0 + n;
            float v = 0.f;
            if (node < N_NODES) {
                int kk = kc * 64 + k;
                if (LAYER1) {
                    v = (kk < 64) ? agg[(size_t)node * 64 + kk]
                                  : ((node < N_USERS)
                                         ? ue[(size_t)node * 64 + (kk - 64)]
                                         : me[(size_t)(node - N_USERS) * 64 + (kk - 64)]);
                } else {
                    v = Ain[(size_t)node * 128 + kk];
                }
            }
            As[k][n] = v;
        }
        __syncthreads();

#pragma unroll 4
        for (int k = 0; k < 64; ++k) {
            float4 w1 = *(const float4*)&Ws[k][oc * 4];
            float4 w2 = *(const float4*)&Ws[k][64 + oc * 4];
            float4 a1 = *(const float4*)&As[k][nc * 4];
            float4 a2 = *(const float4*)&As[k][64 + nc * 4];
            float wv[8] = {w1.x, w1.y, w1.z, w1.w, w2.x, w2.y, w2.z, w2.w};
            float av[8] = {a1.x, a1.y, a1.z, a1.w, a2.x, a2.y, a2.z, a2.w};
#pragma unroll
            for (int n = 0; n < 8; ++n)
#pragma unroll
                for (int o = 0; o < 8; ++o)
                    acc[n][o] += av[n] * wv[o];
        }
        __syncthreads();
    }

    // epilogue
    float bb[8];
    if (LAYER1) {
#pragma unroll
        for (int j = 0; j < 4; ++j) {
            bb[j]     = bias[oc * 4 + j];
            bb[4 + j] = bias[64 + oc * 4 + j];
        }
    }
#pragma unroll
    for (int hn = 0; hn < 2; ++hn) {
#pragma unroll
        for (int j = 0; j < 4; ++j) {
            int node = n0 + hn * 64 + nc * 4 + j;
            if (node < N_NODES) {
#pragma unroll
                for (int ho = 0; ho < 2; ++ho) {
                    float4 r;
                    float* a = &acc[hn * 4 + j][ho * 4];
                    if (LAYER1) {
                        r.x = fmaxf(a[0] + bb[ho * 4 + 0], 0.f);
                        r.y = fmaxf(a[1] + bb[ho * 4 + 1], 0.f);
                        r.z = fmaxf(a[2] + bb[ho * 4 + 2], 0.f);
                        r.w = fmaxf(a[3] + bb[ho * 4 + 3], 0.f);
                    } else {
                        r.x = a[0]; r.y = a[1]; r.z = a[2]; r.w = a[3];
                    }
                    *(float4*)&C[(size_t)node * 128 + ho * 64 + oc * 4] = r;
                }
            }
        }
    }
}

// ---------------------------------------------------------------------------
// gather2 + final: out[n][lane] = mean_nbrs(H[src][lane]) + H[n][64+lane] + b2
// (H rows are [z(64) | w(64)] after the in-place layer-2 GEMM)
// ---------------------------------------------------------------------------
__global__ __launch_bounds__(256) void gather2_final(const int* __restrict__ row_ptr,
                                                     const int* __restrict__ srclist,
                                                     const float* __restrict__ H,
                                                     const float* __restrict__ b2,
                                                     float* __restrict__ out) {
    int w    = (blockIdx.x * 256 + threadIdx.x) >> 6;
    int lane = threadIdx.x & 63;
    if (w >= N_NODES) return;
    int s0 = row_ptr[w], s1 = row_ptr[w + 1];
    float acc = 0.f;
    int i = s0;
    for (; i + 1 < s1; i += 2) {
        int a = srclist[i], b = srclist[i + 1];
        float v0 = H[(size_t)a * 128 + lane];
        float v1 = H[(size_t)b * 128 + lane];
        acc += v0;
        acc += v1;
    }
    if (i < s1) acc += H[(size_t)srclist[i] * 128 + lane];
    float d = fmaxf((float)(s1 - s0), 1.0f);
    out[(size_t)w * 64 + lane] = acc / d + H[(size_t)w * 128 + 64 + lane] + b2[lane];
}

// ---------------------------------------------------------------------------
// Launch
// ---------------------------------------------------------------------------
extern "C" void kernel_launch(void* const* d_in, const int* in_sizes, int n_in,
                              void* d_out, int out_size, void* d_ws, size_t ws_size,
                              hipStream_t stream) {
    const int*   ei  = (const int*)d_in[0];
    const float* ue  = (const float*)d_in[1];
    const float* me  = (const float*)d_in[2];
    const float* W1l = (const float*)d_in[3];
    const float* b1  = (const float*)d_in[4];
    const float* W1r = (const float*)d_in[5];
    const float* W2l = (const float*)d_in[6];
    const float* b2  = (const float*)d_in[7];
    const float* W2r = (const float*)d_in[8];
    float* out = (float*)d_out;

    // ws: row_ptr | srclist | Wt1 | Wt2 | H[150000][128]   (~81.6 MB)
    char* p = (char*)d_ws;
    int* row_ptr = (int*)p;   p += (((N_NODES + 1) * 4) + 255) / 256 * 256;
    int* srclist = (int*)p;   p += (size_t)N_EDGES * 4;
    float* Wt1   = (float*)p; p += 128 * 128 * 4;
    float* Wt2   = (float*)p; p += 128 * 128 * 4;
    float* H     = (float*)p;                       // 150000*128 f32
    int* cnt  = (int*)H;                            // overlay, dead before gemm1
    int* bsum = cnt + N_NODES;
    float* agg1 = out;                              // stage agg1 in d_out

    const int NB = (N_NODES + 1023) / 1024;

    hipMemsetAsync(cnt, 0, N_NODES * sizeof(int), stream);
    csr_count<<<(N_EDGES + 255) / 256, 256, 0, stream>>>(ei, cnt);
    scan1<<<NB, 256, 0, stream>>>(cnt, row_ptr, bsum);
    scan2<<<1, 256, 0, stream>>>(bsum, NB);
    scan3<<<NB, 256, 0, stream>>>(row_ptr, bsum, cnt /*fill*/);
    csr_fill<<<(N_EDGES + 255) / 256, 256, 0, stream>>>(ei, cnt /*fill*/, srclist);
    build_wt<<<64, 256, 0, stream>>>(W1l, W1r, W2l, W2r, Wt1, Wt2);

    int gblocks = (N_NODES * 64 + 255) / 256;
    int mblocks = (N_NODES + 127) / 128;

    gather1<<<gblocks, 256, 0, stream>>>(row_ptr, srclist, ue, me, agg1);
    gemm128<true><<<mblocks, 256, 0, stream>>>(nullptr, agg1, ue, me, Wt1, b1, H);
    gemm128<false><<<mblocks, 256, 0, stream>>>(H, nullptr, nullptr, nullptr, Wt2, nullptr, H);
    gather2_final<<<gblocks, 256, 0, stream>>>(row_ptr, srclist, H, b2, out);
}

// Round 4
// 404.115 us; speedup vs baseline: 2.2123x; 1.2160x over previous
//
#include <hip/hip_runtime.h>

constexpr int N_USERS  = 100000;
constexpr int N_MOVIES = 50000;
constexpr int N_NODES  = N_USERS + N_MOVIES;   // 150000
constexpr int N_EDGES  = 1000000;

// ---------------------------------------------------------------------------
// CSR build: count -> scan(3 kernels) -> fill
// ---------------------------------------------------------------------------
__global__ __launch_bounds__(256) void csr_count(const int* __restrict__ ei,
                                                 int* __restrict__ cnt) {
    int e = blockIdx.x * 256 + threadIdx.x;
    if (e < N_EDGES) atomicAdd(&cnt[ei[N_EDGES + e]], 1);
}

__global__ __launch_bounds__(256) void scan1(const int* __restrict__ cnt,
                                             int* __restrict__ part,
                                             int* __restrict__ bsum) {
    __shared__ int sh[256];
    int t = threadIdx.x, b = blockIdx.x;
    int base = b * 1024 + t * 4;
    int v[4]; int s = 0;
#pragma unroll
    for (int j = 0; j < 4; ++j) {
        int i = base + j;
        v[j] = (i < N_NODES) ? cnt[i] : 0;
        s += v[j];
    }
    sh[t] = s; __syncthreads();
    for (int off = 1; off < 256; off <<= 1) {
        int x = (t >= off) ? sh[t - off] : 0;
        __syncthreads();
        sh[t] += x;
        __syncthreads();
    }
    int run = sh[t] - s;
#pragma unroll
    for (int j = 0; j < 4; ++j) {
        int i = base + j;
        if (i < N_NODES) part[i] = run;
        run += v[j];
    }
    if (t == 255) bsum[b] = sh[255];
}

__global__ __launch_bounds__(256) void scan2(int* __restrict__ bsum, int nb) {
    __shared__ int sh[256];
    int t = threadIdx.x;
    int v = (t < nb) ? bsum[t] : 0;
    sh[t] = v; __syncthreads();
    for (int off = 1; off < 256; off <<= 1) {
        int x = (t >= off) ? sh[t - off] : 0;
        __syncthreads();
        sh[t] += x;
        __syncthreads();
    }
    if (t < nb) bsum[t] = sh[t] - v;
}

__global__ __launch_bounds__(256) void scan3(int* __restrict__ row_ptr,
                                             const int* __restrict__ bsum,
                                             int* __restrict__ fill) {
    int t = threadIdx.x, b = blockIdx.x;
    int base = b * 1024 + t * 4;
    int add = bsum[b];
#pragma unroll
    for (int j = 0; j < 4; ++j) {
        int i = base + j;
        if (i < N_NODES) {
            int r = row_ptr[i] + add;
            row_ptr[i] = r;
            fill[i] = r;
        }
    }
    if (b == 0 && t == 0) row_ptr[N_NODES] = N_EDGES;
}

__global__ __launch_bounds__(256) void csr_fill(const int* __restrict__ ei,
                                                int* __restrict__ fill,
                                                int* __restrict__ srclist) {
    int e = blockIdx.x * 256 + threadIdx.x;
    if (e < N_EDGES) {
        int dst = ei[N_EDGES + e];
        int pos = atomicAdd(&fill[dst], 1);
        srclist[pos] = ei[e];
    }
}

// ---------------------------------------------------------------------------
// Pre-transposed weights (k-major):
//   Wt1[k][o] = k<64 ? W1l[o][k] : W1r[o][k-64]   (layer1 K-concat [agg|x])
//   Wt2[k][o] = o<64 ? W2l[o][k] : W2r[o-64][k]   (layer2 O-concat -> [z|w])
// ---------------------------------------------------------------------------
__global__ __launch_bounds__(256) void build_wt(const float* __restrict__ W1l,
                                                const float* __restrict__ W1r,
                                                const float* __restrict__ W2l,
                                                const float* __restrict__ W2r,
                                                float* __restrict__ Wt1,
                                                float* __restrict__ Wt2) {
    int i = blockIdx.x * 256 + threadIdx.x;
    if (i < 128 * 128) {
        int k = i >> 7, o = i & 127;
        Wt1[i] = (k < 64) ? W1l[o * 64 + k] : W1r[o * 64 + (k - 64)];
        Wt2[i] = (o < 64) ? W2l[o * 128 + k] : W2r[(o - 64) * 128 + k];
    }
}

// ---------------------------------------------------------------------------
// float4 shfl-xor helper (64-lane wave)
// ---------------------------------------------------------------------------
__device__ inline void red4(float4& a, int m) {
    a.x += __shfl_xor(a.x, m, 64);
    a.y += __shfl_xor(a.y, m, 64);
    a.z += __shfl_xor(a.z, m, 64);
    a.w += __shfl_xor(a.w, m, 64);
}

// ---------------------------------------------------------------------------
// gather1: agg[n][:] = mean over neighbors of x[src][:]
// One wave per node; 4 neighbor-slots x 16 lanes x float4 (4 nbrs in flight).
// ---------------------------------------------------------------------------
__global__ __launch_bounds__(256) void gather1(const int* __restrict__ row_ptr,
                                               const int* __restrict__ srclist,
                                               const float* __restrict__ ue,
                                               const float* __restrict__ me,
                                               float* __restrict__ agg) {
    int w    = (blockIdx.x * 256 + threadIdx.x) >> 6;
    int lane = threadIdx.x & 63;
    if (w >= N_NODES) return;
    int s  = lane >> 4;          // neighbor slot 0..3
    int c  = lane & 15;          // float4 channel chunk
    int s0 = row_ptr[w], s1 = row_ptr[w + 1];
    float4 acc = {0.f, 0.f, 0.f, 0.f};
    for (int i = s0 + s; i < s1; i += 4) {
        int a = srclist[i];
        const float* pa = (a < N_USERS) ? ue + (size_t)a * 64
                                        : me + (size_t)(a - N_USERS) * 64;
        float4 v = *(const float4*)&pa[c * 4];
        acc.x += v.x; acc.y += v.y; acc.z += v.z; acc.w += v.w;
    }
    red4(acc, 16);
    red4(acc, 32);
    if (s == 0) {
        float d = fmaxf((float)(s1 - s0), 1.0f);
        float4 r = {acc.x / d, acc.y / d, acc.z / d, acc.w / d};
        *(float4*)&agg[(size_t)w * 64 + c * 4] = r;
    }
}

// ---------------------------------------------------------------------------
// gather2 + final: out[n][:] = mean_nbrs(H[src][0:64]) + H[n][64:128] + b2
// ---------------------------------------------------------------------------
__global__ __launch_bounds__(256) void gather2_final(const int* __restrict__ row_ptr,
                                                     const int* __restrict__ srclist,
                                                     const float* __restrict__ H,
                                                     const float* __restrict__ b2,
                                                     float* __restrict__ out) {
    int w    = (blockIdx.x * 256 + threadIdx.x) >> 6;
    int lane = threadIdx.x & 63;
    if (w >= N_NODES) return;
    int s  = lane >> 4;
    int c  = lane & 15;
    int s0 = row_ptr[w], s1 = row_ptr[w + 1];
    float4 acc = {0.f, 0.f, 0.f, 0.f};
    for (int i = s0 + s; i < s1; i += 4) {
        int a = srclist[i];
        float4 v = *(const float4*)&H[(size_t)a * 128 + c * 4];
        acc.x += v.x; acc.y += v.y; acc.z += v.z; acc.w += v.w;
    }
    red4(acc, 16);
    red4(acc, 32);
    if (s == 0) {
        float d = fmaxf((float)(s1 - s0), 1.0f);
        float4 wv = *(const float4*)&H[(size_t)w * 128 + 64 + c * 4];
        float4 bb = *(const float4*)&b2[c * 4];
        float4 r;
        r.x = acc.x / d + wv.x + bb.x;
        r.y = acc.y / d + wv.y + bb.y;
        r.z = acc.z / d + wv.z + bb.z;
        r.w = acc.w / d + wv.w + bb.w;
        *(float4*)&out[(size_t)w * 64 + c * 4] = r;
    }
}

// ---------------------------------------------------------------------------
// gemm128 v2: C[n][o] = sum_k A[n][k] * Wt[k][o]  (+bias,relu if LAYER1)
// M-tile 256 nodes, N=128 och, K=128 in 4 chunks of 32.
// 256 threads; thread tile 16 nodes x 8 och (LDS:VALU demand 1.125).
// Node idx: {h*64 + nc*4 + j}, och idx: {ho*64 + oc*4 + j} -> <=2-way LDS
// bank aliasing on all inner-loop reads. Staging float4-vectorized.
// LAYER1: A-row = [agg(64) | x(64)]. LAYER2: in-place on H (block reads only
// rows it later overwrites; all reads precede epilogue stores).
// ---------------------------------------------------------------------------
template <bool LAYER1>
__global__ __launch_bounds__(256) void gemm128(const float* Ain,
                                               const float* __restrict__ agg,
                                               const float* __restrict__ ue,
                                               const float* __restrict__ me,
                                               const float* __restrict__ Wt,
                                               const float* __restrict__ bias,
                                               float* C) {
    __shared__ float As[32][260];   // [k][n], pad 256+4
    __shared__ float Ws[32][128];   // [k][o], no pad needed

    const int tid = threadIdx.x;
    const int n0  = blockIdx.x * 256;
    const int oc  = tid & 15;    // och group: {oc*4..+3} and {64+oc*4..+3}
    const int nc  = tid >> 4;    // node group: {h*64 + nc*4..+3}, h=0..3

    float acc[16][8] = {};       // [node(h*4+j)][och(ho*4+j)]

    const int sc4 = tid & 7;     // staging: float4 k-chunk
    const int sn  = tid >> 3;    // staging: node base (0..31, step 32)

    for (int kc = 0; kc < 4; ++kc) {
        // --- stage Ws: linear float4 copy (coalesced, conflict-light) ---
#pragma unroll
        for (int r = 0; r < 4; ++r) {
            int i = r * 1024 + tid * 4;
            int k = i >> 7, o = i & 127;
            *(float4*)&Ws[k][o] = *(const float4*)&Wt[(kc * 32 + k) * 128 + o];
        }
        // --- stage As: float4 global read along k, transposed LDS write ---
#pragma unroll
        for (int r = 0; r < 8; ++r) {
            int n = r * 32 + sn;
            int node = n0 + n;
            int kk = kc * 32 + sc4 * 4;
            float4 v = {0.f, 0.f, 0.f, 0.f};
            if (node < N_NODES) {
                if (LAYER1) {
                    v = (kk < 64)
                        ? *(const float4*)&agg[(size_t)node * 64 + kk]
                        : ((node < N_USERS)
                               ? *(const float4*)&ue[(size_t)node * 64 + (kk - 64)]
                               : *(const float4*)&me[(size_t)(node - N_USERS) * 64 + (kk - 64)]);
                } else {
                    v = *(const float4*)&Ain[(size_t)node * 128 + kk];
                }
            }
            int kl = sc4 * 4;
            As[kl + 0][n] = v.x;
            As[kl + 1][n] = v.y;
            As[kl + 2][n] = v.z;
            As[kl + 3][n] = v.w;
        }
        __syncthreads();

#pragma unroll 4
        for (int k = 0; k < 32; ++k) {
            float4 w1 = *(const float4*)&Ws[k][oc * 4];
            float4 w2 = *(const float4*)&Ws[k][64 + oc * 4];
            float wv[8] = {w1.x, w1.y, w1.z, w1.w, w2.x, w2.y, w2.z, w2.w};
            float av[16];
#pragma unroll
            for (int h = 0; h < 4; ++h) {
                float4 a4 = *(const float4*)&As[k][h * 64 + nc * 4];
                av[h * 4 + 0] = a4.x; av[h * 4 + 1] = a4.y;
                av[h * 4 + 2] = a4.z; av[h * 4 + 3] = a4.w;
            }
#pragma unroll
            for (int n = 0; n < 16; ++n)
#pragma unroll
                for (int o = 0; o < 8; ++o)
                    acc[n][o] += av[n] * wv[o];
        }
        __syncthreads();
    }

    // --- epilogue ---
    float bb[8];
    if (LAYER1) {
#pragma unroll
        for (int j = 0; j < 4; ++j) {
            bb[j]     = bias[oc * 4 + j];
            bb[4 + j] = bias[64 + oc * 4 + j];
        }
    }
#pragma unroll
    for (int h = 0; h < 4; ++h) {
#pragma unroll
        for (int j = 0; j < 4; ++j) {
            int node = n0 + h * 64 + nc * 4 + j;
            if (node < N_NODES) {
                float* a = acc[h * 4 + j];
#pragma unroll
                for (int ho = 0; ho < 2; ++ho) {
                    float4 r;
                    if (LAYER1) {
                        r.x = fmaxf(a[ho * 4 + 0] + bb[ho * 4 + 0], 0.f);
                        r.y = fmaxf(a[ho * 4 + 1] + bb[ho * 4 + 1], 0.f);
                        r.z = fmaxf(a[ho * 4 + 2] + bb[ho * 4 + 2], 0.f);
                        r.w = fmaxf(a[ho * 4 + 3] + bb[ho * 4 + 3], 0.f);
                    } else {
                        r.x = a[ho * 4 + 0]; r.y = a[ho * 4 + 1];
                        r.z = a[ho * 4 + 2]; r.w = a[ho * 4 + 3];
                    }
                    *(float4*)&C[(size_t)node * 128 + ho * 64 + oc * 4] = r;
                }
            }
        }
    }
}

// ---------------------------------------------------------------------------
// Launch
// ---------------------------------------------------------------------------
extern "C" void kernel_launch(void* const* d_in, const int* in_sizes, int n_in,
                              void* d_out, int out_size, void* d_ws, size_t ws_size,
                              hipStream_t stream) {
    const int*   ei  = (const int*)d_in[0];
    const float* ue  = (const float*)d_in[1];
    const float* me  = (const float*)d_in[2];
    const float* W1l = (const float*)d_in[3];
    const float* b1  = (const float*)d_in[4];
    const float* W1r = (const float*)d_in[5];
    const float* W2l = (const float*)d_in[6];
    const float* b2  = (const float*)d_in[7];
    const float* W2r = (const float*)d_in[8];
    float* out = (float*)d_out;

    // ws: row_ptr | srclist | Wt1 | Wt2 | H[150000][128]   (~81.6 MB)
    char* p = (char*)d_ws;
    int* row_ptr = (int*)p;   p += (((N_NODES + 1) * 4) + 255) / 256 * 256;
    int* srclist = (int*)p;   p += (size_t)N_EDGES * 4;
    float* Wt1   = (float*)p; p += 128 * 128 * 4;
    float* Wt2   = (float*)p; p += 128 * 128 * 4;
    float* H     = (float*)p;                       // 150000*128 f32
    int* cnt  = (int*)H;                            // overlay, dead before gemm1
    int* bsum = cnt + N_NODES;
    float* agg1 = out;                              // stage agg1 in d_out

    const int NB = (N_NODES + 1023) / 1024;

    hipMemsetAsync(cnt, 0, N_NODES * sizeof(int), stream);
    csr_count<<<(N_EDGES + 255) / 256, 256, 0, stream>>>(ei, cnt);
    scan1<<<NB, 256, 0, stream>>>(cnt, row_ptr, bsum);
    scan2<<<1, 256, 0, stream>>>(bsum, NB);
    scan3<<<NB, 256, 0, stream>>>(row_ptr, bsum, cnt /*fill*/);
    csr_fill<<<(N_EDGES + 255) / 256, 256, 0, stream>>>(ei, cnt /*fill*/, srclist);
    build_wt<<<64, 256, 0, stream>>>(W1l, W1r, W2l, W2r, Wt1, Wt2);

    int gblocks = (N_NODES * 64 + 255) / 256;
    int mblocks = (N_NODES + 255) / 256;

    gather1<<<gblocks, 256, 0, stream>>>(row_ptr, srclist, ue, me, agg1);
    gemm128<true><<<mblocks, 256, 0, stream>>>(nullptr, agg1, ue, me, Wt1, b1, H);
    gemm128<false><<<mblocks, 256, 0, stream>>>(H, nullptr, nullptr, nullptr, Wt2, nullptr, H);
    gather2_final<<<gblocks, 256, 0, stream>>>(row_ptr, srclist, H, b2, out);
}

// Round 6
// 324.801 us; speedup vs baseline: 2.7525x; 1.2442x over previous
//
#include <hip/hip_runtime.h>

constexpr int N_USERS  = 100000;
constexpr int N_MOVIES = 50000;
constexpr int N_NODES  = N_USERS + N_MOVIES;   // 150000
constexpr int N_EDGES  = 1000000;

typedef __attribute__((ext_vector_type(8))) short bf16x8;
typedef __attribute__((ext_vector_type(4))) float f32x4;

__device__ inline unsigned short bf16_rne(float x) {
    unsigned u = __float_as_uint(x);
    unsigned r = (u + 0x7FFF + ((u >> 16) & 1)) >> 16;
    return (unsigned short)r;
}

// ---------------------------------------------------------------------------
// CSR build: count -> scan(3 kernels) -> fill
// ---------------------------------------------------------------------------
__global__ __launch_bounds__(256) void csr_count(const int* __restrict__ ei,
                                                 int* __restrict__ cnt) {
    int e = blockIdx.x * 256 + threadIdx.x;
    if (e < N_EDGES) atomicAdd(&cnt[ei[N_EDGES + e]], 1);
}

__global__ __launch_bounds__(256) void scan1(const int* __restrict__ cnt,
                                             int* __restrict__ part,
                                             int* __restrict__ bsum) {
    __shared__ int sh[256];
    int t = threadIdx.x, b = blockIdx.x;
    int base = b * 1024 + t * 4;
    int v[4]; int s = 0;
#pragma unroll
    for (int j = 0; j < 4; ++j) {
        int i = base + j;
        v[j] = (i < N_NODES) ? cnt[i] : 0;
        s += v[j];
    }
    sh[t] = s; __syncthreads();
    for (int off = 1; off < 256; off <<= 1) {
        int x = (t >= off) ? sh[t - off] : 0;
        __syncthreads();
        sh[t] += x;
        __syncthreads();
    }
    int run = sh[t] - s;
#pragma unroll
    for (int j = 0; j < 4; ++j) {
        int i = base + j;
        if (i < N_NODES) part[i] = run;
        run += v[j];
    }
    if (t == 255) bsum[b] = sh[255];
}

__global__ __launch_bounds__(256) void scan2(int* __restrict__ bsum, int nb) {
    __shared__ int sh[256];
    int t = threadIdx.x;
    int v = (t < nb) ? bsum[t] : 0;
    sh[t] = v; __syncthreads();
    for (int off = 1; off < 256; off <<= 1) {
        int x = (t >= off) ? sh[t - off] : 0;
        __syncthreads();
        sh[t] += x;
        __syncthreads();
    }
    if (t < nb) bsum[t] = sh[t] - v;
}

__global__ __launch_bounds__(256) void scan3(int* __restrict__ row_ptr,
                                             const int* __restrict__ bsum,
                                             int* __restrict__ fill) {
    int t = threadIdx.x, b = blockIdx.x;
    int base = b * 1024 + t * 4;
    int add = bsum[b];
#pragma unroll
    for (int j = 0; j < 4; ++j) {
        int i = base + j;
        if (i < N_NODES) {
            int r = row_ptr[i] + add;
            row_ptr[i] = r;
            fill[i] = r;
        }
    }
    if (b == 0 && t == 0) row_ptr[N_NODES] = N_EDGES;
}

__global__ __launch_bounds__(256) void csr_fill(const int* __restrict__ ei,
                                                int* __restrict__ fill,
                                                int* __restrict__ srclist) {
    int e = blockIdx.x * 256 + threadIdx.x;
    if (e < N_EDGES) {
        int dst = ei[N_EDGES + e];
        int pos = atomicAdd(&fill[dst], 1);
        srclist[pos] = ei[e];
    }
}

// ---------------------------------------------------------------------------
// Prepack weights into MFMA B-fragment order, split into bf16 hi/lo.
// Element index: i = ((layer*4 + kc)*8 + oc)*64*8 + lane*8 + j
//   k = kc*32 + (lane>>4)*8 + j ; o = oc*16 + (lane&15)
// layer0: W[k][o] = k<64 ? W1l[o][k] : W1r[o][k-64]   (layer1 K-concat)
// layer1: W[k][o] = o<64 ? W2l[o][k] : W2r[o-64][k]   (layer2 O-concat)
// ---------------------------------------------------------------------------
__global__ __launch_bounds__(256) void prepack_w(const float* __restrict__ W1l,
                                                 const float* __restrict__ W1r,
                                                 const float* __restrict__ W2l,
                                                 const float* __restrict__ W2r,
                                                 unsigned short* __restrict__ whi,
                                                 unsigned short* __restrict__ wlo) {
    int i = blockIdx.x * 256 + threadIdx.x;
    if (i >= 2 * 128 * 128) return;
    int layer = i >> 14;
    int r     = i & 16383;
    int kc    = r >> 12;
    int oc    = (r >> 9) & 7;
    int lane  = (r >> 3) & 63;
    int j     = r & 7;
    int k = kc * 32 + (lane >> 4) * 8 + j;
    int o = oc * 16 + (lane & 15);
    float v;
    if (layer == 0) v = (k < 64) ? W1l[o * 64 + k] : W1r[o * 64 + (k - 64)];
    else            v = (o < 64) ? W2l[o * 128 + k] : W2r[(o - 64) * 128 + k];
    unsigned short hi = bf16_rne(v);
    float fhi = __uint_as_float((unsigned)hi << 16);
    unsigned short lo = bf16_rne(v - fhi);
    whi[i] = hi;
    wlo[i] = lo;
}

// ---------------------------------------------------------------------------
// float4 shfl-xor helper (64-lane wave)
// ---------------------------------------------------------------------------
__device__ inline void red4(float4& a, int m) {
    a.x += __shfl_xor(a.x, m, 64);
    a.y += __shfl_xor(a.y, m, 64);
    a.z += __shfl_xor(a.z, m, 64);
    a.w += __shfl_xor(a.w, m, 64);
}

// ---------------------------------------------------------------------------
// gather1: agg[n][:] = mean over neighbors of x[src][:]
// ---------------------------------------------------------------------------
__global__ __launch_bounds__(256) void gather1(const int* __restrict__ row_ptr,
                                               const int* __restrict__ srclist,
                                               const float* __restrict__ ue,
                                               const float* __restrict__ me,
                                               float* __restrict__ agg) {
    int w    = (blockIdx.x * 256 + threadIdx.x) >> 6;
    int lane = threadIdx.x & 63;
    if (w >= N_NODES) return;
    int s  = lane >> 4;
    int c  = lane & 15;
    int s0 = row_ptr[w], s1 = row_ptr[w + 1];
    float4 acc = {0.f, 0.f, 0.f, 0.f};
    for (int i = s0 + s; i < s1; i += 4) {
        int a = srclist[i];
        const float* pa = (a < N_USERS) ? ue + (size_t)a * 64
                                        : me + (size_t)(a - N_USERS) * 64;
        float4 v = *(const float4*)&pa[c * 4];
        acc.x += v.x; acc.y += v.y; acc.z += v.z; acc.w += v.w;
    }
    red4(acc, 16);
    red4(acc, 32);
    if (s == 0) {
        float d = fmaxf((float)(s1 - s0), 1.0f);
        float4 r = {acc.x / d, acc.y / d, acc.z / d, acc.w / d};
        *(float4*)&agg[(size_t)w * 64 + c * 4] = r;
    }
}

// ---------------------------------------------------------------------------
// gather2 + final: out[n][:] = mean_nbrs(H[src][0:64]) + H[n][64:128] + b2
// ---------------------------------------------------------------------------
__global__ __launch_bounds__(256) void gather2_final(const int* __restrict__ row_ptr,
                                                     const int* __restrict__ srclist,
                                                     const float* __restrict__ H,
                                                     const float* __restrict__ b2,
                                                     float* __restrict__ out) {
    int w    = (blockIdx.x * 256 + threadIdx.x) >> 6;
    int lane = threadIdx.x & 63;
    if (w >= N_NODES) return;
    int s  = lane >> 4;
    int c  = lane & 15;
    int s0 = row_ptr[w], s1 = row_ptr[w + 1];
    float4 acc = {0.f, 0.f, 0.f, 0.f};
    for (int i = s0 + s; i < s1; i += 4) {
        int a = srclist[i];
        float4 v = *(const float4*)&H[(size_t)a * 128 + c * 4];
        acc.x += v.x; acc.y += v.y; acc.z += v.z; acc.w += v.w;
    }
    red4(acc, 16);
    red4(acc, 32);
    if (s == 0) {
        float d = fmaxf((float)(s1 - s0), 1.0f);
        float4 wv = *(const float4*)&H[(size_t)w * 128 + 64 + c * 4];
        float4 bb = *(const float4*)&b2[c * 4];
        float4 r;
        r.x = acc.x / d + wv.x + bb.x;
        r.y = acc.y / d + wv.y + bb.y;
        r.z = acc.z / d + wv.z + bb.z;
        r.w = acc.w / d + wv.w + bb.w;
        *(float4*)&out[(size_t)w * 64 + c * 4] = r;
    }
}

// ---------------------------------------------------------------------------
// gemm_mfma: C[n][o] = sum_k A[n][k] * W[k][o]  (+bias, relu if LAYER1)
// bf16x3 split: A = ah + al, W = wh + wl; acc += ah*wh + ah*wl + al*wh.
// M-tile 128/block, 4 waves; wave handles rows [n0, n0+32) (2 row-frags)
// x all 8 col-frags. No LDS, no barriers. A loaded global->reg. W from
// prepacked frags (16B/lane coalesced). D frag: col=lane&15,
// row=(lane>>4)*4+reg. LAYER2 in-place on H: each wave reads only the 32
// rows it overwrites; all reads precede its epilogue stores.
// ---------------------------------------------------------------------------
template <bool LAYER1>
__global__ __launch_bounds__(256) void gemm_mfma(const float* Ain,
                                                 const float* __restrict__ agg,
                                                 const float* __restrict__ ue,
                                                 const float* __restrict__ me,
                                                 const unsigned short* __restrict__ whi,
                                                 const unsigned short* __restrict__ wlo,
                                                 const float* __restrict__ bias,
                                                 float* C) {
    const int tid  = threadIdx.x;
    const int w    = tid >> 6;
    const int lane = tid & 63;
    const int n0   = blockIdx.x * 128 + w * 32;
    const int lr   = lane & 15;    // A row / C col within frag
    const int lg   = lane >> 4;    // k-group / C row-group

    f32x4 acc[2][8] = {};          // [row-frag][col-frag], all static-indexed

    // fragment-group base (units of 64-lane x 8-elem groups): layer1 at 2048
    const int wbase = LAYER1 ? 0 : 2048;

    for (int kc = 0; kc < 4; ++kc) {
        const int k0 = kc * 32 + lg * 8;
        // --- A fragments: global -> reg, bf16 hi/lo split ---
        bf16x8 ah[2], al[2];
#pragma unroll
        for (int f = 0; f < 2; ++f) {
            int node = n0 + f * 16 + lr;
            float av[8];
#pragma unroll
            for (int j = 0; j < 8; ++j) av[j] = 0.f;
            if (node < N_NODES) {
                const float* src;
                if (LAYER1) {
                    if (k0 < 64) src = &agg[(size_t)node * 64 + k0];
                    else if (node < N_USERS) src = &ue[(size_t)node * 64 + (k0 - 64)];
                    else src = &me[(size_t)(node - N_USERS) * 64 + (k0 - 64)];
                } else {
                    src = &Ain[(size_t)node * 128 + k0];
                }
                float4 v0 = *(const float4*)src;
                float4 v1 = *(const float4*)(src + 4);
                av[0] = v0.x; av[1] = v0.y; av[2] = v0.z; av[3] = v0.w;
                av[4] = v1.x; av[5] = v1.y; av[6] = v1.z; av[7] = v1.w;
            }
#pragma unroll
            for (int j = 0; j < 8; ++j) {
                unsigned short h = bf16_rne(av[j]);
                float fh = __uint_as_float((unsigned)h << 16);
                unsigned short lo = bf16_rne(av[j] - fh);
                ah[f][j] = (short)h;
                al[f][j] = (short)lo;
            }
        }
        // --- W fragments + MFMA ---
#pragma unroll
        for (int oc = 0; oc < 8; ++oc) {
            size_t widx = ((size_t)(wbase + (kc * 8 + oc) * 64 + lane)) * 8;
            bf16x8 wh = *(const bf16x8*)&whi[widx];
            bf16x8 wl = *(const bf16x8*)&wlo[widx];
#pragma unroll
            for (int f = 0; f < 2; ++f) {
                acc[f][oc] = __builtin_amdgcn_mfma_f32_16x16x32_bf16(ah[f], wh, acc[f][oc], 0, 0, 0);
                acc[f][oc] = __builtin_amdgcn_mfma_f32_16x16x32_bf16(ah[f], wl, acc[f][oc], 0, 0, 0);
                acc[f][oc] = __builtin_amdgcn_mfma_f32_16x16x32_bf16(al[f], wh, acc[f][oc], 0, 0, 0);
            }
        }
    }

    // --- epilogue: C[row][col] = acc (+bias, relu) ---
#pragma unroll
    for (int f = 0; f < 2; ++f) {
#pragma unroll
        for (int oc = 0; oc < 8; ++oc) {
            int col = oc * 16 + lr;
            float b = LAYER1 ? bias[col] : 0.f;
#pragma unroll
            for (int i = 0; i < 4; ++i) {
                int row = n0 + f * 16 + lg * 4 + i;
                if (row < N_NODES) {
                    float v = acc[f][oc][i] + b;
                    if (LAYER1) v = fmaxf(v, 0.f);
                    C[(size_t)row * 128 + col] = v;
                }
            }
        }
    }
}

// ---------------------------------------------------------------------------
// Launch
// ---------------------------------------------------------------------------
extern "C" void kernel_launch(void* const* d_in, const int* in_sizes, int n_in,
                              void* d_out, int out_size, void* d_ws, size_t ws_size,
                              hipStream_t stream) {
    const int*   ei  = (const int*)d_in[0];
    const float* ue  = (const float*)d_in[1];
    const float* me  = (const float*)d_in[2];
    const float* W1l = (const float*)d_in[3];
    const float* b1  = (const float*)d_in[4];
    const float* W1r = (const float*)d_in[5];
    const float* W2l = (const float*)d_in[6];
    const float* b2  = (const float*)d_in[7];
    const float* W2r = (const float*)d_in[8];
    float* out = (float*)d_out;

    // ws: row_ptr | srclist | whi[32768] | wlo[32768] | H[150000][128]
    char* p = (char*)d_ws;
    int* row_ptr = (int*)p;              p += (((N_NODES + 1) * 4) + 255) / 256 * 256;
    int* srclist = (int*)p;              p += (size_t)N_EDGES * 4;
    unsigned short* whi = (unsigned short*)p; p += 2 * 128 * 128 * 2;
    unsigned short* wlo = (unsigned short*)p; p += 2 * 128 * 128 * 2;
    float* H     = (float*)p;            // 150000*128 f32 (76.8 MB)
    int* cnt  = (int*)H;                 // overlay, dead before gemm1
    int* bsum = cnt + N_NODES;
    float* agg1 = out;                   // stage agg1 in d_out

    const int NB = (N_NODES + 1023) / 1024;

    hipMemsetAsync(cnt, 0, N_NODES * sizeof(int), stream);
    csr_count<<<(N_EDGES + 255) / 256, 256, 0, stream>>>(ei, cnt);
    scan1<<<NB, 256, 0, stream>>>(cnt, row_ptr, bsum);
    scan2<<<1, 256, 0, stream>>>(bsum, NB);
    scan3<<<NB, 256, 0, stream>>>(row_ptr, bsum, cnt /*fill*/);
    csr_fill<<<(N_EDGES + 255) / 256, 256, 0, stream>>>(ei, cnt /*fill*/, srclist);
    prepack_w<<<(2 * 128 * 128 + 255) / 256, 256, 0, stream>>>(W1l, W1r, W2l, W2r, whi, wlo);

    int gblocks = (N_NODES * 64 + 255) / 256;
    int mblocks = (N_NODES + 127) / 128;

    gather1<<<gblocks, 256, 0, stream>>>(row_ptr, srclist, ue, me, agg1);
    gemm_mfma<true><<<mblocks, 256, 0, stream>>>(nullptr, agg1, ue, me, whi, wlo, b1, H);
    gemm_mfma<false><<<mblocks, 256, 0, stream>>>(H, nullptr, nullptr, nullptr, whi, wlo, nullptr, H);
    gather2_final<<<gblocks, 256, 0, stream>>>(row_ptr, srclist, H, b2, out);
}

// Round 7
// 269.264 us; speedup vs baseline: 3.3202x; 1.2063x over previous
//
#include <hip/hip_runtime.h>

constexpr int N_USERS  = 100000;
constexpr int N_MOVIES = 50000;
constexpr int N_NODES  = N_USERS + N_MOVIES;   // 150000
constexpr int N_EDGES  = 1000000;

typedef __attribute__((ext_vector_type(8))) short bf16x8;
typedef __attribute__((ext_vector_type(4))) float f32x4;

__device__ inline unsigned short bf16_rne(float x) {
    unsigned u = __float_as_uint(x);
    unsigned r = (u + 0x7FFF + ((u >> 16) & 1)) >> 16;
    return (unsigned short)r;
}

// ---------------------------------------------------------------------------
// CSR build v2: ord-pass (single atomic pass; cnt -> degrees, ord -> within-
// node ordinal) -> scan(3 kernels) -> scatter-pass (no atomics).
// ---------------------------------------------------------------------------
__global__ __launch_bounds__(256) void csr_ord(const int* __restrict__ ei,
                                               int* __restrict__ cnt,
                                               int* __restrict__ ord) {
    int t  = blockIdx.x * 256 + threadIdx.x;
    int e0 = t * 4;
    if (e0 + 3 < N_EDGES) {
        int4 d = *(const int4*)&ei[N_EDGES + e0];
        int4 o;
        o.x = atomicAdd(&cnt[d.x], 1);
        o.y = atomicAdd(&cnt[d.y], 1);
        o.z = atomicAdd(&cnt[d.z], 1);
        o.w = atomicAdd(&cnt[d.w], 1);
        *(int4*)&ord[e0] = o;
    } else {
        for (int e = e0; e < N_EDGES; ++e)
            ord[e] = atomicAdd(&cnt[ei[N_EDGES + e]], 1);
    }
}

__global__ __launch_bounds__(256) void csr_scatter(const int* __restrict__ ei,
                                                   const int* __restrict__ row_ptr,
                                                   const int* __restrict__ ord,
                                                   int* __restrict__ srclist) {
    int t  = blockIdx.x * 256 + threadIdx.x;
    int e0 = t * 4;
    if (e0 + 3 < N_EDGES) {
        int4 s = *(const int4*)&ei[e0];
        int4 d = *(const int4*)&ei[N_EDGES + e0];
        int4 o = *(const int4*)&ord[e0];
        srclist[row_ptr[d.x] + o.x] = s.x;
        srclist[row_ptr[d.y] + o.y] = s.y;
        srclist[row_ptr[d.z] + o.z] = s.z;
        srclist[row_ptr[d.w] + o.w] = s.w;
    } else {
        for (int e = e0; e < N_EDGES; ++e)
            srclist[row_ptr[ei[N_EDGES + e]] + ord[e]] = ei[e];
    }
}

// 1024 elems/block (256 thr x 4), exclusive scan partials + block sums
__global__ __launch_bounds__(256) void scan1(const int* __restrict__ cnt,
                                             int* __restrict__ part,
                                             int* __restrict__ bsum) {
    __shared__ int sh[256];
    int t = threadIdx.x, b = blockIdx.x;
    int base = b * 1024 + t * 4;
    int v[4]; int s = 0;
#pragma unroll
    for (int j = 0; j < 4; ++j) {
        int i = base + j;
        v[j] = (i < N_NODES) ? cnt[i] : 0;
        s += v[j];
    }
    sh[t] = s; __syncthreads();
    for (int off = 1; off < 256; off <<= 1) {
        int x = (t >= off) ? sh[t - off] : 0;
        __syncthreads();
        sh[t] += x;
        __syncthreads();
    }
    int run = sh[t] - s;
#pragma unroll
    for (int j = 0; j < 4; ++j) {
        int i = base + j;
        if (i < N_NODES) part[i] = run;
        run += v[j];
    }
    if (t == 255) bsum[b] = sh[255];
}

__global__ __launch_bounds__(256) void scan2(int* __restrict__ bsum, int nb) {
    __shared__ int sh[256];
    int t = threadIdx.x;
    int v = (t < nb) ? bsum[t] : 0;
    sh[t] = v; __syncthreads();
    for (int off = 1; off < 256; off <<= 1) {
        int x = (t >= off) ? sh[t - off] : 0;
        __syncthreads();
        sh[t] += x;
        __syncthreads();
    }
    if (t < nb) bsum[t] = sh[t] - v;
}

__global__ __launch_bounds__(256) void scan3(int* __restrict__ row_ptr,
                                             const int* __restrict__ bsum) {
    int t = threadIdx.x, b = blockIdx.x;
    int base = b * 1024 + t * 4;
    int add = bsum[b];
#pragma unroll
    for (int j = 0; j < 4; ++j) {
        int i = base + j;
        if (i < N_NODES) row_ptr[i] += add;
    }
    if (b == 0 && t == 0) row_ptr[N_NODES] = N_EDGES;
}

// ---------------------------------------------------------------------------
// Prepack weights into MFMA B-fragment order, split into bf16 hi/lo.
// Element index: i = ((layer*4 + kc)*8 + oc)*64*8 + lane*8 + j
//   k = kc*32 + (lane>>4)*8 + j ; o = oc*16 + (lane&15)
// layer0: W[k][o] = k<64 ? W1l[o][k] : W1r[o][k-64]   (layer1 K-concat)
// layer1: W[k][o] = o<64 ? W2l[o][k] : W2r[o-64][k]   (layer2 O-concat)
// ---------------------------------------------------------------------------
__global__ __launch_bounds__(256) void prepack_w(const float* __restrict__ W1l,
                                                 const float* __restrict__ W1r,
                                                 const float* __restrict__ W2l,
                                                 const float* __restrict__ W2r,
                                                 unsigned short* __restrict__ whi,
                                                 unsigned short* __restrict__ wlo) {
    int i = blockIdx.x * 256 + threadIdx.x;
    if (i >= 2 * 128 * 128) return;
    int layer = i >> 14;
    int r     = i & 16383;
    int kc    = r >> 12;
    int oc    = (r >> 9) & 7;
    int lane  = (r >> 3) & 63;
    int j     = r & 7;
    int k = kc * 32 + (lane >> 4) * 8 + j;
    int o = oc * 16 + (lane & 15);
    float v;
    if (layer == 0) v = (k < 64) ? W1l[o * 64 + k] : W1r[o * 64 + (k - 64)];
    else            v = (o < 64) ? W2l[o * 128 + k] : W2r[(o - 64) * 128 + k];
    unsigned short hi = bf16_rne(v);
    float fhi = __uint_as_float((unsigned)hi << 16);
    unsigned short lo = bf16_rne(v - fhi);
    whi[i] = hi;
    wlo[i] = lo;
}

// ---------------------------------------------------------------------------
// float4 shfl-xor helper (64-lane wave)
// ---------------------------------------------------------------------------
__device__ inline void red4(float4& a, int m) {
    a.x += __shfl_xor(a.x, m, 64);
    a.y += __shfl_xor(a.y, m, 64);
    a.z += __shfl_xor(a.z, m, 64);
    a.w += __shfl_xor(a.w, m, 64);
}

// ---------------------------------------------------------------------------
// gather1: agg[n][:] = mean over neighbors of x[src][:]
// One wave per node; 4 neighbor-slots x 16 lanes x float4.
// ---------------------------------------------------------------------------
__global__ __launch_bounds__(256) void gather1(const int* __restrict__ row_ptr,
                                               const int* __restrict__ srclist,
                                               const float* __restrict__ ue,
                                               const float* __restrict__ me,
                                               float* __restrict__ agg) {
    int w    = (blockIdx.x * 256 + threadIdx.x) >> 6;
    int lane = threadIdx.x & 63;
    if (w >= N_NODES) return;
    int s  = lane >> 4;
    int c  = lane & 15;
    int s0 = row_ptr[w], s1 = row_ptr[w + 1];
    float4 acc = {0.f, 0.f, 0.f, 0.f};
    for (int i = s0 + s; i < s1; i += 4) {
        int a = srclist[i];
        const float* pa = (a < N_USERS) ? ue + (size_t)a * 64
                                        : me + (size_t)(a - N_USERS) * 64;
        float4 v = *(const float4*)&pa[c * 4];
        acc.x += v.x; acc.y += v.y; acc.z += v.z; acc.w += v.w;
    }
    red4(acc, 16);
    red4(acc, 32);
    if (s == 0) {
        float d = fmaxf((float)(s1 - s0), 1.0f);
        float4 r = {acc.x / d, acc.y / d, acc.z / d, acc.w / d};
        *(float4*)&agg[(size_t)w * 64 + c * 4] = r;
    }
}

// ---------------------------------------------------------------------------
// gather2 + final: out[n][:] = mean_nbrs(H[src][0:64]) + H[n][64:128] + b2
// ---------------------------------------------------------------------------
__global__ __launch_bounds__(256) void gather2_final(const int* __restrict__ row_ptr,
                                                     const int* __restrict__ srclist,
                                                     const float* __restrict__ H,
                                                     const float* __restrict__ b2,
                                                     float* __restrict__ out) {
    int w    = (blockIdx.x * 256 + threadIdx.x) >> 6;
    int lane = threadIdx.x & 63;
    if (w >= N_NODES) return;
    int s  = lane >> 4;
    int c  = lane & 15;
    int s0 = row_ptr[w], s1 = row_ptr[w + 1];
    float4 acc = {0.f, 0.f, 0.f, 0.f};
    for (int i = s0 + s; i < s1; i += 4) {
        int a = srclist[i];
        float4 v = *(const float4*)&H[(size_t)a * 128 + c * 4];
        acc.x += v.x; acc.y += v.y; acc.z += v.z; acc.w += v.w;
    }
    red4(acc, 16);
    red4(acc, 32);
    if (s == 0) {
        float d = fmaxf((float)(s1 - s0), 1.0f);
        float4 wv = *(const float4*)&H[(size_t)w * 128 + 64 + c * 4];
        float4 bb = *(const float4*)&b2[c * 4];
        float4 r;
        r.x = acc.x / d + wv.x + bb.x;
        r.y = acc.y / d + wv.y + bb.y;
        r.z = acc.z / d + wv.z + bb.z;
        r.w = acc.w / d + wv.w + bb.w;
        *(float4*)&out[(size_t)w * 64 + c * 4] = r;
    }
}

// ---------------------------------------------------------------------------
// gemm_mfma: C[n][o] = sum_k A[n][k] * W[k][o]  (+bias, relu if LAYER1)
// bf16x3 split: A = ah + al, W = wh + wl; acc += ah*wh + ah*wl + al*wh.
// M-tile 128/block, 4 waves; wave handles rows [n0, n0+32) (2 row-frags)
// x all 8 col-frags. No LDS, no barriers. A loaded global->reg. W from
// prepacked frags (16B/lane coalesced). D frag: col=lane&15,
// row=(lane>>4)*4+reg. LAYER2 in-place on H: each wave reads only the 32
// rows it overwrites; all reads precede its epilogue stores.
// ---------------------------------------------------------------------------
template <bool LAYER1>
__global__ __launch_bounds__(256) void gemm_mfma(const float* Ain,
                                                 const float* __restrict__ agg,
                                                 const float* __restrict__ ue,
                                                 const float* __restrict__ me,
                                                 const unsigned short* __restrict__ whi,
                                                 const unsigned short* __restrict__ wlo,
                                                 const float* __restrict__ bias,
                                                 float* C) {
    const int tid  = threadIdx.x;
    const int w    = tid >> 6;
    const int lane = tid & 63;
    const int n0   = blockIdx.x * 128 + w * 32;
    const int lr   = lane & 15;    // A row / C col within frag
    const int lg   = lane >> 4;    // k-group / C row-group

    f32x4 acc[2][8] = {};          // [row-frag][col-frag], all static-indexed

    // fragment-group base (units of 64-lane x 8-elem groups): layer1 at 2048
    const int wbase = LAYER1 ? 0 : 2048;

    for (int kc = 0; kc < 4; ++kc) {
        const int k0 = kc * 32 + lg * 8;
        // --- A fragments: global -> reg, bf16 hi/lo split ---
        bf16x8 ah[2], al[2];
#pragma unroll
        for (int f = 0; f < 2; ++f) {
            int node = n0 + f * 16 + lr;
            float av[8];
#pragma unroll
            for (int j = 0; j < 8; ++j) av[j] = 0.f;
            if (node < N_NODES) {
                const float* src;
                if (LAYER1) {
                    if (k0 < 64) src = &agg[(size_t)node * 64 + k0];
                    else if (node < N_USERS) src = &ue[(size_t)node * 64 + (k0 - 64)];
                    else src = &me[(size_t)(node - N_USERS) * 64 + (k0 - 64)];
                } else {
                    src = &Ain[(size_t)node * 128 + k0];
                }
                float4 v0 = *(const float4*)src;
                float4 v1 = *(const float4*)(src + 4);
                av[0] = v0.x; av[1] = v0.y; av[2] = v0.z; av[3] = v0.w;
                av[4] = v1.x; av[5] = v1.y; av[6] = v1.z; av[7] = v1.w;
            }
#pragma unroll
            for (int j = 0; j < 8; ++j) {
                unsigned short h = bf16_rne(av[j]);
                float fh = __uint_as_float((unsigned)h << 16);
                unsigned short lo = bf16_rne(av[j] - fh);
                ah[f][j] = (short)h;
                al[f][j] = (short)lo;
            }
        }
        // --- W fragments + MFMA ---
#pragma unroll
        for (int oc = 0; oc < 8; ++oc) {
            size_t widx = ((size_t)(wbase + (kc * 8 + oc) * 64 + lane)) * 8;
            bf16x8 wh = *(const bf16x8*)&whi[widx];
            bf16x8 wl = *(const bf16x8*)&wlo[widx];
#pragma unroll
            for (int f = 0; f < 2; ++f) {
                acc[f][oc] = __builtin_amdgcn_mfma_f32_16x16x32_bf16(ah[f], wh, acc[f][oc], 0, 0, 0);
                acc[f][oc] = __builtin_amdgcn_mfma_f32_16x16x32_bf16(ah[f], wl, acc[f][oc], 0, 0, 0);
                acc[f][oc] = __builtin_amdgcn_mfma_f32_16x16x32_bf16(al[f], wh, acc[f][oc], 0, 0, 0);
            }
        }
    }

    // --- epilogue: C[row][col] = acc (+bias, relu) ---
#pragma unroll
    for (int f = 0; f < 2; ++f) {
#pragma unroll
        for (int oc = 0; oc < 8; ++oc) {
            int col = oc * 16 + lr;
            float b = LAYER1 ? bias[col] : 0.f;
#pragma unroll
            for (int i = 0; i < 4; ++i) {
                int row = n0 + f * 16 + lg * 4 + i;
                if (row < N_NODES) {
                    float v = acc[f][oc][i] + b;
                    if (LAYER1) v = fmaxf(v, 0.f);
                    C[(size_t)row * 128 + col] = v;
                }
            }
        }
    }
}

// ---------------------------------------------------------------------------
// Launch
// ---------------------------------------------------------------------------
extern "C" void kernel_launch(void* const* d_in, const int* in_sizes, int n_in,
                              void* d_out, int out_size, void* d_ws, size_t ws_size,
                              hipStream_t stream) {
    const int*   ei  = (const int*)d_in[0];
    const float* ue  = (const float*)d_in[1];
    const float* me  = (const float*)d_in[2];
    const float* W1l = (const float*)d_in[3];
    const float* b1  = (const float*)d_in[4];
    const float* W1r = (const float*)d_in[5];
    const float* W2l = (const float*)d_in[6];
    const float* b2  = (const float*)d_in[7];
    const float* W2r = (const float*)d_in[8];
    float* out = (float*)d_out;

    // ws: row_ptr | srclist | ord | whi | wlo | H[150000][128]  (~85.7 MB)
    char* p = (char*)d_ws;
    int* row_ptr = (int*)p;              p += (((N_NODES + 1) * 4) + 255) / 256 * 256;
    int* srclist = (int*)p;              p += (size_t)N_EDGES * 4;
    int* ord     = (int*)p;              p += (size_t)N_EDGES * 4;
    unsigned short* whi = (unsigned short*)p; p += 2 * 128 * 128 * 2;
    unsigned short* wlo = (unsigned short*)p; p += 2 * 128 * 128 * 2;
    float* H     = (float*)p;            // 150000*128 f32 (76.8 MB)
    int* cnt  = (int*)H;                 // overlay, dead after scan1
    int* bsum = cnt + N_NODES;
    float* agg1 = out;                   // stage agg1 in d_out

    const int NB = (N_NODES + 1023) / 1024;
    const int EB4 = (N_EDGES / 4 + 255) / 256;   // 4-edge-per-thread grids

    hipMemsetAsync(cnt, 0, N_NODES * sizeof(int), stream);
    csr_ord<<<EB4, 256, 0, stream>>>(ei, cnt, ord);
    scan1<<<NB, 256, 0, stream>>>(cnt, row_ptr, bsum);
    scan2<<<1, 256, 0, stream>>>(bsum, NB);
    scan3<<<NB, 256, 0, stream>>>(row_ptr, bsum);
    csr_scatter<<<EB4, 256, 0, stream>>>(ei, row_ptr, ord, srclist);
    prepack_w<<<(2 * 128 * 128 + 255) / 256, 256, 0, stream>>>(W1l, W1r, W2l, W2r, whi, wlo);

    int gblocks = (N_NODES * 64 + 255) / 256;
    int mblocks = (N_NODES + 127) / 128;

    gather1<<<gblocks, 256, 0, stream>>>(row_ptr, srclist, ue, me, agg1);
    gemm_mfma<true><<<mblocks, 256, 0, stream>>>(nullptr, agg1, ue, me, whi, wlo, b1, H);
    gemm_mfma<false><<<mblocks, 256, 0, stream>>>(H, nullptr, nullptr, nullptr, whi, wlo, nullptr, H);
    gather2_final<<<gblocks, 256, 0, stream>>>(row_ptr, srclist, H, b2, out);
}

// Round 8
// 244.936 us; speedup vs baseline: 3.6500x; 1.0993x over previous
//
#include <hip/hip_runtime.h>

constexpr int N_USERS  = 100000;
constexpr int N_MOVIES = 50000;
constexpr int N_NODES  = N_USERS + N_MOVIES;   // 150000
constexpr int N_EDGES  = 1000000;

typedef __attribute__((ext_vector_type(8))) short bf16x8;
typedef __attribute__((ext_vector_type(8))) unsigned short usx8;
typedef __attribute__((ext_vector_type(4))) float f32x4;

__device__ inline unsigned short bf16_rne(float x) {
    unsigned u = __float_as_uint(x);
    unsigned r = (u + 0x7FFF + ((u >> 16) & 1)) >> 16;
    return (unsigned short)r;
}
__device__ inline float bf16_to_f(short v) {
    return __uint_as_float(((unsigned)(unsigned short)v) << 16);
}

// ---------------------------------------------------------------------------
// CSR build: ord-pass (atomics; cnt->degrees, ord->ordinal) -> scan ->
// scatter-pass (no atomics).
// ---------------------------------------------------------------------------
__global__ __launch_bounds__(256) void csr_ord(const int* __restrict__ ei,
                                               int* __restrict__ cnt,
                                               int* __restrict__ ord) {
    int t  = blockIdx.x * 256 + threadIdx.x;
    int e0 = t * 4;
    if (e0 + 3 < N_EDGES) {
        int4 d = *(const int4*)&ei[N_EDGES + e0];
        int4 o;
        o.x = atomicAdd(&cnt[d.x], 1);
        o.y = atomicAdd(&cnt[d.y], 1);
        o.z = atomicAdd(&cnt[d.z], 1);
        o.w = atomicAdd(&cnt[d.w], 1);
        *(int4*)&ord[e0] = o;
    } else {
        for (int e = e0; e < N_EDGES; ++e)
            ord[e] = atomicAdd(&cnt[ei[N_EDGES + e]], 1);
    }
}

__global__ __launch_bounds__(256) void csr_scatter(const int* __restrict__ ei,
                                                   const int* __restrict__ row_ptr,
                                                   const int* __restrict__ ord,
                                                   int* __restrict__ srclist) {
    int t  = blockIdx.x * 256 + threadIdx.x;
    int e0 = t * 4;
    if (e0 + 3 < N_EDGES) {
        int4 s = *(const int4*)&ei[e0];
        int4 d = *(const int4*)&ei[N_EDGES + e0];
        int4 o = *(const int4*)&ord[e0];
        srclist[row_ptr[d.x] + o.x] = s.x;
        srclist[row_ptr[d.y] + o.y] = s.y;
        srclist[row_ptr[d.z] + o.z] = s.z;
        srclist[row_ptr[d.w] + o.w] = s.w;
    } else {
        for (int e = e0; e < N_EDGES; ++e)
            srclist[row_ptr[ei[N_EDGES + e]] + ord[e]] = ei[e];
    }
}

__global__ __launch_bounds__(256) void scan1(const int* __restrict__ cnt,
                                             int* __restrict__ part,
                                             int* __restrict__ bsum) {
    __shared__ int sh[256];
    int t = threadIdx.x, b = blockIdx.x;
    int base = b * 1024 + t * 4;
    int v[4]; int s = 0;
#pragma unroll
    for (int j = 0; j < 4; ++j) {
        int i = base + j;
        v[j] = (i < N_NODES) ? cnt[i] : 0;
        s += v[j];
    }
    sh[t] = s; __syncthreads();
    for (int off = 1; off < 256; off <<= 1) {
        int x = (t >= off) ? sh[t - off] : 0;
        __syncthreads();
        sh[t] += x;
        __syncthreads();
    }
    int run = sh[t] - s;
#pragma unroll
    for (int j = 0; j < 4; ++j) {
        int i = base + j;
        if (i < N_NODES) part[i] = run;
        run += v[j];
    }
    if (t == 255) bsum[b] = sh[255];
}

__global__ __launch_bounds__(256) void scan2(int* __restrict__ bsum, int nb) {
    __shared__ int sh[256];
    int t = threadIdx.x;
    int v = (t < nb) ? bsum[t] : 0;
    sh[t] = v; __syncthreads();
    for (int off = 1; off < 256; off <<= 1) {
        int x = (t >= off) ? sh[t - off] : 0;
        __syncthreads();
        sh[t] += x;
        __syncthreads();
    }
    if (t < nb) bsum[t] = sh[t] - v;
}

__global__ __launch_bounds__(256) void scan3(int* __restrict__ row_ptr,
                                             const int* __restrict__ bsum) {
    int t = threadIdx.x, b = blockIdx.x;
    int base = b * 1024 + t * 4;
    int add = bsum[b];
#pragma unroll
    for (int j = 0; j < 4; ++j) {
        int i = base + j;
        if (i < N_NODES) row_ptr[i] += add;
    }
    if (b == 0 && t == 0) row_ptr[N_NODES] = N_EDGES;
}

// ---------------------------------------------------------------------------
// prepack_w: weights -> MFMA B-fragment order, bf16.
// Element index: i = ((layer*4 + kc)*8 + oc)*512 + lane*8 + j
//   k = kc*32 + (lane>>4)*8 + j ; o = oc*16 + (lane&15)
// layer0: W[k][o] = k<64 ? W1l[o][k] : W1r[o][k-64]   (layer1 K-concat)
// layer1: W[k][o] = o<64 ? W2l[o][k] : W2r[o-64][k]   (layer2 O-concat)
// ---------------------------------------------------------------------------
__global__ __launch_bounds__(256) void prepack_w(const float* __restrict__ W1l,
                                                 const float* __restrict__ W1r,
                                                 const float* __restrict__ W2l,
                                                 const float* __restrict__ W2r,
                                                 unsigned short* __restrict__ wb) {
    int i = blockIdx.x * 256 + threadIdx.x;
    if (i >= 2 * 128 * 128) return;
    int layer = i >> 14;
    int r     = i & 16383;
    int kc    = r >> 12;
    int oc    = (r >> 9) & 7;
    int lane  = (r >> 3) & 63;
    int j     = r & 7;
    int k = kc * 32 + (lane >> 4) * 8 + j;
    int o = oc * 16 + (lane & 15);
    float v;
    if (layer == 0) v = (k < 64) ? W1l[o * 64 + k] : W1r[o * 64 + (k - 64)];
    else            v = (o < 64) ? W2l[o * 128 + k] : W2r[(o - 64) * 128 + k];
    wb[i] = bf16_rne(v);
}

// ---------------------------------------------------------------------------
// pack_x: xb[n][64] bf16 <- concat(ue, me)
// ---------------------------------------------------------------------------
__global__ __launch_bounds__(256) void pack_x(const float* __restrict__ ue,
                                              const float* __restrict__ me,
                                              unsigned short* __restrict__ xb) {
    int i = blockIdx.x * 256 + threadIdx.x;   // over N_NODES*8
    if (i >= N_NODES * 8) return;
    int n = i >> 3, c = (i & 7) * 8;
    const float* src = (n < N_USERS) ? &ue[(size_t)n * 64 + c]
                                     : &me[(size_t)(n - N_USERS) * 64 + c];
    float4 v0 = *(const float4*)src;
    float4 v1 = *(const float4*)(src + 4);
    usx8 r;
    r[0] = bf16_rne(v0.x); r[1] = bf16_rne(v0.y);
    r[2] = bf16_rne(v0.z); r[3] = bf16_rne(v0.w);
    r[4] = bf16_rne(v1.x); r[5] = bf16_rne(v1.y);
    r[6] = bf16_rne(v1.z); r[7] = bf16_rne(v1.w);
    *(usx8*)&xb[(size_t)n * 64 + c] = r;
}

// ---------------------------------------------------------------------------
// gather1: aggb[n][:] = bf16(mean over neighbors of xb[src][:])
// One wave per node: 8 neighbor-slots x 8 lanes x bf16x8 (16B).
// ---------------------------------------------------------------------------
__global__ __launch_bounds__(256) void gather1(const int* __restrict__ row_ptr,
                                               const int* __restrict__ srclist,
                                               const unsigned short* __restrict__ xb,
                                               unsigned short* __restrict__ aggb) {
    int w    = (blockIdx.x * 256 + threadIdx.x) >> 6;
    int lane = threadIdx.x & 63;
    if (w >= N_NODES) return;
    int s = lane >> 3;          // slot 0..7
    int l = lane & 7;           // channel-octet
    int s0 = row_ptr[w], s1 = row_ptr[w + 1];
    float acc[8] = {};
    for (int i = s0 + s; i < s1; i += 8) {
        int a = srclist[i];
        bf16x8 v = *(const bf16x8*)&xb[(size_t)a * 64 + l * 8];
#pragma unroll
        for (int j = 0; j < 8; ++j) acc[j] += bf16_to_f(v[j]);
    }
#pragma unroll
    for (int m = 8; m <= 32; m <<= 1)
#pragma unroll
        for (int j = 0; j < 8; ++j) acc[j] += __shfl_xor(acc[j], m, 64);
    if (s == 0) {
        float d = fmaxf((float)(s1 - s0), 1.0f);
        usx8 r;
#pragma unroll
        for (int j = 0; j < 8; ++j) r[j] = bf16_rne(acc[j] / d);
        *(usx8*)&aggb[(size_t)w * 64 + l * 8] = r;
    }
}

// ---------------------------------------------------------------------------
// gather2 + final: out[n][:] = mean_nbrs(zb[src][:]) + wf[n][:] + b2
// ---------------------------------------------------------------------------
__global__ __launch_bounds__(256) void gather2_final(const int* __restrict__ row_ptr,
                                                     const int* __restrict__ srclist,
                                                     const unsigned short* __restrict__ zb,
                                                     const float* __restrict__ wf,
                                                     const float* __restrict__ b2,
                                                     float* __restrict__ out) {
    int w    = (blockIdx.x * 256 + threadIdx.x) >> 6;
    int lane = threadIdx.x & 63;
    if (w >= N_NODES) return;
    int s = lane >> 3;
    int l = lane & 7;
    int s0 = row_ptr[w], s1 = row_ptr[w + 1];
    float acc[8] = {};
    for (int i = s0 + s; i < s1; i += 8) {
        int a = srclist[i];
        bf16x8 v = *(const bf16x8*)&zb[(size_t)a * 64 + l * 8];
#pragma unroll
        for (int j = 0; j < 8; ++j) acc[j] += bf16_to_f(v[j]);
    }
#pragma unroll
    for (int m = 8; m <= 32; m <<= 1)
#pragma unroll
        for (int j = 0; j < 8; ++j) acc[j] += __shfl_xor(acc[j], m, 64);
    if (s == 0) {
        float d = fmaxf((float)(s1 - s0), 1.0f);
        float4 w0 = *(const float4*)&wf[(size_t)w * 64 + l * 8];
        float4 w1 = *(const float4*)&wf[(size_t)w * 64 + l * 8 + 4];
        float4 c0 = *(const float4*)&b2[l * 8];
        float4 c1 = *(const float4*)&b2[l * 8 + 4];
        float4 r0, r1;
        r0.x = acc[0] / d + w0.x + c0.x;
        r0.y = acc[1] / d + w0.y + c0.y;
        r0.z = acc[2] / d + w0.z + c0.z;
        r0.w = acc[3] / d + w0.w + c0.w;
        r1.x = acc[4] / d + w1.x + c1.x;
        r1.y = acc[5] / d + w1.y + c1.y;
        r1.z = acc[6] / d + w1.z + c1.z;
        r1.w = acc[7] / d + w1.w + c1.w;
        *(float4*)&out[(size_t)w * 64 + l * 8]     = r0;
        *(float4*)&out[(size_t)w * 64 + l * 8 + 4] = r1;
    }
}

// ---------------------------------------------------------------------------
// gemm_bf16: C = A @ W (+bias, relu) in pure bf16 inputs, fp32 accum.
// M-tile 128/block, 4 waves; wave = rows [n0, n0+32) (2 row-frags) x 8
// col-frags; K = 128 in 4 chunks of 32. No LDS, no barriers, no conversion:
// A frags load directly as bf16x8.
// LAYER1: A = [aggb | xb] (K-concat), out = h1b bf16 [n][128].
// LAYER2: A = h1b, out = zb bf16 [n][64] (oc<4) + wf fp32 [n][64] (oc>=4).
//   wf aliases h1b rows byte-exactly (row n at byte n*256); each wave fully
//   consumes its 32 rows of h1b in the K-loop before its epilogue stores.
// ---------------------------------------------------------------------------
template <bool LAYER1>
__global__ __launch_bounds__(256) void gemm_bf16(const unsigned short* Ab,
                                                 const unsigned short* __restrict__ xb,
                                                 const unsigned short* __restrict__ wb,
                                                 const float* __restrict__ bias,
                                                 unsigned short* outb,
                                                 float* outf) {
    const int tid  = threadIdx.x;
    const int w    = tid >> 6;
    const int lane = tid & 63;
    const int n0   = blockIdx.x * 128 + w * 32;
    const int lr   = lane & 15;    // A row / C col within frag
    const int lg   = lane >> 4;    // k-group / C row-group

    f32x4 acc[2][8] = {};
    const int wbase = LAYER1 ? 0 : 2048;   // fragment-group units (x8 elems)

    for (int kc = 0; kc < 4; ++kc) {
        const int k0 = kc * 32 + lg * 8;
        bf16x8 a[2];
#pragma unroll
        for (int f = 0; f < 2; ++f) {
            int node = n0 + f * 16 + lr;
            bf16x8 z = {};
            a[f] = z;
            if (node < N_NODES) {
                const unsigned short* ap;
                if (LAYER1)
                    ap = (k0 < 64) ? &Ab[(size_t)node * 64 + k0]
                                   : &xb[(size_t)node * 64 + (k0 - 64)];
                else
                    ap = &Ab[(size_t)node * 128 + k0];
                a[f] = *(const bf16x8*)ap;
            }
        }
#pragma unroll
        for (int oc = 0; oc < 8; ++oc) {
            size_t widx = ((size_t)(wbase + (kc * 8 + oc) * 64 + lane)) * 8;
            bf16x8 wfrag = *(const bf16x8*)&wb[widx];
#pragma unroll
            for (int f = 0; f < 2; ++f)
                acc[f][oc] = __builtin_amdgcn_mfma_f32_16x16x32_bf16(a[f], wfrag, acc[f][oc], 0, 0, 0);
        }
    }

    // epilogue: D frag col=lane&15, row=(lane>>4)*4+i
#pragma unroll
    for (int f = 0; f < 2; ++f) {
#pragma unroll
        for (int oc = 0; oc < 8; ++oc) {
            int col = oc * 16 + lr;
            float b = LAYER1 ? bias[col] : 0.f;
#pragma unroll
            for (int i = 0; i < 4; ++i) {
                int row = n0 + f * 16 + lg * 4 + i;
                if (row < N_NODES) {
                    float v = acc[f][oc][i] + b;
                    if (LAYER1) {
                        outb[(size_t)row * 128 + col] = bf16_rne(fmaxf(v, 0.f));
                    } else {
                        if (oc < 4) outb[(size_t)row * 64 + col] = bf16_rne(v);
                        else        outf[(size_t)row * 64 + (col - 64)] = v;
                    }
                }
            }
        }
    }
}

// ---------------------------------------------------------------------------
// Launch
// ---------------------------------------------------------------------------
extern "C" void kernel_launch(void* const* d_in, const int* in_sizes, int n_in,
                              void* d_out, int out_size, void* d_ws, size_t ws_size,
                              hipStream_t stream) {
    const int*   ei  = (const int*)d_in[0];
    const float* ue  = (const float*)d_in[1];
    const float* me  = (const float*)d_in[2];
    const float* W1l = (const float*)d_in[3];
    const float* b1  = (const float*)d_in[4];
    const float* W1r = (const float*)d_in[5];
    const float* W2l = (const float*)d_in[6];
    const float* b2  = (const float*)d_in[7];
    const float* W2r = (const float*)d_in[8];
    float* out = (float*)d_out;

    // ws: row_ptr | srclist | ord | wb | xb | h1b (alias wf) | zb  (~85.5 MB)
    char* p = (char*)d_ws;
    int* row_ptr = (int*)p;                   p += (((N_NODES + 1) * 4) + 255) / 256 * 256;
    int* srclist = (int*)p;                   p += (size_t)N_EDGES * 4;
    int* ord     = (int*)p;                   p += (size_t)N_EDGES * 4;
    unsigned short* wb = (unsigned short*)p;  p += 2 * 128 * 128 * 2;
    unsigned short* xb = (unsigned short*)p;  p += (size_t)N_NODES * 64 * 2;
    unsigned short* h1b = (unsigned short*)p; p += (size_t)N_NODES * 128 * 2;
    unsigned short* zb  = (unsigned short*)p; p += (size_t)N_NODES * 64 * 2;
    float* wf = (float*)h1b;                  // byte-exact row alias (see gemm)
    int* cnt  = (int*)h1b;                    // overlay, dead after scan1
    int* bsum = cnt + N_NODES;
    unsigned short* aggb = (unsigned short*)out;   // staged in d_out

    const int NB  = (N_NODES + 1023) / 1024;
    const int EB4 = (N_EDGES / 4 + 255) / 256;

    hipMemsetAsync(cnt, 0, N_NODES * sizeof(int), stream);
    csr_ord<<<EB4, 256, 0, stream>>>(ei, cnt, ord);
    scan1<<<NB, 256, 0, stream>>>(cnt, row_ptr, bsum);
    scan2<<<1, 256, 0, stream>>>(bsum, NB);
    scan3<<<NB, 256, 0, stream>>>(row_ptr, bsum);
    csr_scatter<<<EB4, 256, 0, stream>>>(ei, row_ptr, ord, srclist);
    prepack_w<<<(2 * 128 * 128 + 255) / 256, 256, 0, stream>>>(W1l, W1r, W2l, W2r, wb);
    pack_x<<<(N_NODES * 8 + 255) / 256, 256, 0, stream>>>(ue, me, xb);

    int gblocks = (N_NODES * 64 + 255) / 256;
    int mblocks = (N_NODES + 127) / 128;

    gather1<<<gblocks, 256, 0, stream>>>(row_ptr, srclist, xb, aggb);
    gemm_bf16<true><<<mblocks, 256, 0, stream>>>(aggb, xb, wb, b1, h1b, nullptr);
    gemm_bf16<false><<<mblocks, 256, 0, stream>>>(h1b, nullptr, wb, nullptr, zb, wf);
    gather2_final<<<gblocks, 256, 0, stream>>>(row_ptr, srclist, zb, wf, b2, out);
}

// Round 9
// 206.817 us; speedup vs baseline: 4.3227x; 1.1843x over previous
//
#include <hip/hip_runtime.h>

constexpr int N_USERS  = 100000;
constexpr int N_MOVIES = 50000;
constexpr int N_NODES  = N_USERS + N_MOVIES;   // 150000
constexpr int N_EDGES  = 1000000;

typedef __attribute__((ext_vector_type(8))) short bf16x8;
typedef __attribute__((ext_vector_type(8))) unsigned short usx8;
typedef __attribute__((ext_vector_type(4))) float f32x4;

__device__ inline unsigned short bf16_rne(float x) {
    unsigned u = __float_as_uint(x);
    unsigned r = (u + 0x7FFF + ((u >> 16) & 1)) >> 16;
    return (unsigned short)r;
}
__device__ inline float bf16_to_f(short v) {
    return __uint_as_float(((unsigned)(unsigned short)v) << 16);
}

// ---------------------------------------------------------------------------
// CSR build: ord-pass (atomics; cnt->degrees, ord->ordinal) -> scan ->
// scatter-pass (no atomics).
// ---------------------------------------------------------------------------
__global__ __launch_bounds__(256) void csr_ord(const int* __restrict__ ei,
                                               int* __restrict__ cnt,
                                               int* __restrict__ ord) {
    int t  = blockIdx.x * 256 + threadIdx.x;
    int e0 = t * 4;
    if (e0 + 3 < N_EDGES) {
        int4 d = *(const int4*)&ei[N_EDGES + e0];
        int4 o;
        o.x = atomicAdd(&cnt[d.x], 1);
        o.y = atomicAdd(&cnt[d.y], 1);
        o.z = atomicAdd(&cnt[d.z], 1);
        o.w = atomicAdd(&cnt[d.w], 1);
        *(int4*)&ord[e0] = o;
    } else {
        for (int e = e0; e < N_EDGES; ++e)
            ord[e] = atomicAdd(&cnt[ei[N_EDGES + e]], 1);
    }
}

__global__ __launch_bounds__(256) void csr_scatter(const int* __restrict__ ei,
                                                   const int* __restrict__ row_ptr,
                                                   const int* __restrict__ ord,
                                                   int* __restrict__ srclist) {
    int t  = blockIdx.x * 256 + threadIdx.x;
    int e0 = t * 4;
    if (e0 + 3 < N_EDGES) {
        int4 s = *(const int4*)&ei[e0];
        int4 d = *(const int4*)&ei[N_EDGES + e0];
        int4 o = *(const int4*)&ord[e0];
        srclist[row_ptr[d.x] + o.x] = s.x;
        srclist[row_ptr[d.y] + o.y] = s.y;
        srclist[row_ptr[d.z] + o.z] = s.z;
        srclist[row_ptr[d.w] + o.w] = s.w;
    } else {
        for (int e = e0; e < N_EDGES; ++e)
            srclist[row_ptr[ei[N_EDGES + e]] + ord[e]] = ei[e];
    }
}

__global__ __launch_bounds__(256) void scan1(const int* __restrict__ cnt,
                                             int* __restrict__ part,
                                             int* __restrict__ bsum) {
    __shared__ int sh[256];
    int t = threadIdx.x, b = blockIdx.x;
    int base = b * 1024 + t * 4;
    int v[4]; int s = 0;
#pragma unroll
    for (int j = 0; j < 4; ++j) {
        int i = base + j;
        v[j] = (i < N_NODES) ? cnt[i] : 0;
        s += v[j];
    }
    sh[t] = s; __syncthreads();
    for (int off = 1; off < 256; off <<= 1) {
        int x = (t >= off) ? sh[t - off] : 0;
        __syncthreads();
        sh[t] += x;
        __syncthreads();
    }
    int run = sh[t] - s;
#pragma unroll
    for (int j = 0; j < 4; ++j) {
        int i = base + j;
        if (i < N_NODES) part[i] = run;
        run += v[j];
    }
    if (t == 255) bsum[b] = sh[255];
}

__global__ __launch_bounds__(256) void scan2(int* __restrict__ bsum, int nb) {
    __shared__ int sh[256];
    int t = threadIdx.x;
    int v = (t < nb) ? bsum[t] : 0;
    sh[t] = v; __syncthreads();
    for (int off = 1; off < 256; off <<= 1) {
        int x = (t >= off) ? sh[t - off] : 0;
        __syncthreads();
        sh[t] += x;
        __syncthreads();
    }
    if (t < nb) bsum[t] = sh[t] - v;
}

__global__ __launch_bounds__(256) void scan3(int* __restrict__ row_ptr,
                                             const int* __restrict__ bsum) {
    int t = threadIdx.x, b = blockIdx.x;
    int base = b * 1024 + t * 4;
    int add = bsum[b];
#pragma unroll
    for (int j = 0; j < 4; ++j) {
        int i = base + j;
        if (i < N_NODES) row_ptr[i] += add;
    }
    if (b == 0 && t == 0) row_ptr[N_NODES] = N_EDGES;
}

// ---------------------------------------------------------------------------
// prepack_w: weights -> MFMA B-fragment order, bf16.
// Element index: i = ((layer*4 + kc)*8 + oc)*512 + lane*8 + j
//   k = kc*32 + (lane>>4)*8 + j ; o = oc*16 + (lane&15)
// layer0: W[k][o] = k<64 ? W1l[o][k] : W1r[o][k-64]   (layer1 K-concat)
// layer1: W[k][o] = o<64 ? W2l[o][k] : W2r[o-64][k]   (layer2 O-concat)
// ---------------------------------------------------------------------------
__global__ __launch_bounds__(256) void prepack_w(const float* __restrict__ W1l,
                                                 const float* __restrict__ W1r,
                                                 const float* __restrict__ W2l,
                                                 const float* __restrict__ W2r,
                                                 unsigned short* __restrict__ wb) {
    int i = blockIdx.x * 256 + threadIdx.x;
    if (i >= 2 * 128 * 128) return;
    int layer = i >> 14;
    int r     = i & 16383;
    int kc    = r >> 12;
    int oc    = (r >> 9) & 7;
    int lane  = (r >> 3) & 63;
    int j     = r & 7;
    int k = kc * 32 + (lane >> 4) * 8 + j;
    int o = oc * 16 + (lane & 15);
    float v;
    if (layer == 0) v = (k < 64) ? W1l[o * 64 + k] : W1r[o * 64 + (k - 64)];
    else            v = (o < 64) ? W2l[o * 128 + k] : W2r[(o - 64) * 128 + k];
    wb[i] = bf16_rne(v);
}

// ---------------------------------------------------------------------------
// pack_x: xb[n][64] bf16 <- concat(ue, me)
// ---------------------------------------------------------------------------
__global__ __launch_bounds__(256) void pack_x(const float* __restrict__ ue,
                                              const float* __restrict__ me,
                                              unsigned short* __restrict__ xb) {
    int i = blockIdx.x * 256 + threadIdx.x;   // over N_NODES*8
    if (i >= N_NODES * 8) return;
    int n = i >> 3, c = (i & 7) * 8;
    const float* src = (n < N_USERS) ? &ue[(size_t)n * 64 + c]
                                     : &me[(size_t)(n - N_USERS) * 64 + c];
    float4 v0 = *(const float4*)src;
    float4 v1 = *(const float4*)(src + 4);
    usx8 r;
    r[0] = bf16_rne(v0.x); r[1] = bf16_rne(v0.y);
    r[2] = bf16_rne(v0.z); r[3] = bf16_rne(v0.w);
    r[4] = bf16_rne(v1.x); r[5] = bf16_rne(v1.y);
    r[6] = bf16_rne(v1.z); r[7] = bf16_rne(v1.w);
    *(usx8*)&xb[(size_t)n * 64 + c] = r;
}

// ---------------------------------------------------------------------------
// gather1 v3: 8 lanes per node (lane group owns a 16B row slice), 8 nodes
// per wave. Each group loops over ALL its node's neighbors: no cross-lane
// reduction, no shuffles. One divide -> 8 multiplies.
// ---------------------------------------------------------------------------
__global__ __launch_bounds__(256) void gather1(const int* __restrict__ row_ptr,
                                               const int* __restrict__ srclist,
                                               const unsigned short* __restrict__ xb,
                                               unsigned short* __restrict__ aggb) {
    int gid = blockIdx.x * 256 + threadIdx.x;
    int n = gid >> 3, l = gid & 7;
    if (n >= N_NODES) return;
    int s0 = row_ptr[n], s1 = row_ptr[n + 1];
    float acc[8] = {};
    for (int i = s0; i < s1; ++i) {
        int a = srclist[i];
        bf16x8 v = *(const bf16x8*)&xb[(size_t)a * 64 + l * 8];
#pragma unroll
        for (int j = 0; j < 8; ++j) acc[j] += bf16_to_f(v[j]);
    }
    float inv = 1.0f / fmaxf((float)(s1 - s0), 1.0f);
    usx8 r;
#pragma unroll
    for (int j = 0; j < 8; ++j) r[j] = bf16_rne(acc[j] * inv);
    *(usx8*)&aggb[(size_t)n * 64 + l * 8] = r;
}

// ---------------------------------------------------------------------------
// gather2+final v3: same structure; out[n][:] = mean_nbrs(zb[src]) + wf[n] + b2
// ---------------------------------------------------------------------------
__global__ __launch_bounds__(256) void gather2_final(const int* __restrict__ row_ptr,
                                                     const int* __restrict__ srclist,
                                                     const unsigned short* __restrict__ zb,
                                                     const float* __restrict__ wf,
                                                     const float* __restrict__ b2,
                                                     float* __restrict__ out) {
    int gid = blockIdx.x * 256 + threadIdx.x;
    int n = gid >> 3, l = gid & 7;
    if (n >= N_NODES) return;
    int s0 = row_ptr[n], s1 = row_ptr[n + 1];
    float acc[8] = {};
    for (int i = s0; i < s1; ++i) {
        int a = srclist[i];
        bf16x8 v = *(const bf16x8*)&zb[(size_t)a * 64 + l * 8];
#pragma unroll
        for (int j = 0; j < 8; ++j) acc[j] += bf16_to_f(v[j]);
    }
    float inv = 1.0f / fmaxf((float)(s1 - s0), 1.0f);
    float4 w0 = *(const float4*)&wf[(size_t)n * 64 + l * 8];
    float4 w1 = *(const float4*)&wf[(size_t)n * 64 + l * 8 + 4];
    float4 c0 = *(const float4*)&b2[l * 8];
    float4 c1 = *(const float4*)&b2[l * 8 + 4];
    float4 r0, r1;
    r0.x = acc[0] * inv + w0.x + c0.x;
    r0.y = acc[1] * inv + w0.y + c0.y;
    r0.z = acc[2] * inv + w0.z + c0.z;
    r0.w = acc[3] * inv + w0.w + c0.w;
    r1.x = acc[4] * inv + w1.x + c1.x;
    r1.y = acc[5] * inv + w1.y + c1.y;
    r1.z = acc[6] * inv + w1.z + c1.z;
    r1.w = acc[7] * inv + w1.w + c1.w;
    *(float4*)&out[(size_t)n * 64 + l * 8]     = r0;
    *(float4*)&out[(size_t)n * 64 + l * 8 + 4] = r1;
}

// ---------------------------------------------------------------------------
// gemm_bf16: C = A @ W (+bias, relu) in pure bf16 inputs, fp32 accum.
// M-tile 128/block, 4 waves; wave = rows [n0, n0+32) (2 row-frags) x 8
// col-frags; K = 128 in 4 chunks of 32. No LDS, no barriers.
// LAYER1: A = [aggb | xb] (K-concat), out = h1b bf16 [n][128].
// LAYER2: A = h1b, out = zb bf16 [n][64] (oc<4) + wf fp32 [n][64] (oc>=4).
//   wf aliases h1b rows byte-exactly; each wave fully consumes its 32 rows
//   of h1b in the K-loop before its epilogue stores.
// ---------------------------------------------------------------------------
template <bool LAYER1>
__global__ __launch_bounds__(256) void gemm_bf16(const unsigned short* Ab,
                                                 const unsigned short* __restrict__ xb,
                                                 const unsigned short* __restrict__ wb,
                                                 const float* __restrict__ bias,
                                                 unsigned short* outb,
                                                 float* outf) {
    const int tid  = threadIdx.x;
    const int w    = tid >> 6;
    const int lane = tid & 63;
    const int n0   = blockIdx.x * 128 + w * 32;
    const int lr   = lane & 15;    // A row / C col within frag
    const int lg   = lane >> 4;    // k-group / C row-group

    f32x4 acc[2][8] = {};
    const int wbase = LAYER1 ? 0 : 2048;   // fragment-group units (x8 elems)

    for (int kc = 0; kc < 4; ++kc) {
        const int k0 = kc * 32 + lg * 8;
        bf16x8 a[2];
#pragma unroll
        for (int f = 0; f < 2; ++f) {
            int node = n0 + f * 16 + lr;
            bf16x8 z = {};
            a[f] = z;
            if (node < N_NODES) {
                const unsigned short* ap;
                if (LAYER1)
                    ap = (k0 < 64) ? &Ab[(size_t)node * 64 + k0]
                                   : &xb[(size_t)node * 64 + (k0 - 64)];
                else
                    ap = &Ab[(size_t)node * 128 + k0];
                a[f] = *(const bf16x8*)ap;
            }
        }
#pragma unroll
        for (int oc = 0; oc < 8; ++oc) {
            size_t widx = ((size_t)(wbase + (kc * 8 + oc) * 64 + lane)) * 8;
            bf16x8 wfrag = *(const bf16x8*)&wb[widx];
#pragma unroll
            for (int f = 0; f < 2; ++f)
                acc[f][oc] = __builtin_amdgcn_mfma_f32_16x16x32_bf16(a[f], wfrag, acc[f][oc], 0, 0, 0);
        }
    }

    // epilogue: D frag col=lane&15, row=(lane>>4)*4+i
#pragma unroll
    for (int f = 0; f < 2; ++f) {
#pragma unroll
        for (int oc = 0; oc < 8; ++oc) {
            int col = oc * 16 + lr;
            float b = LAYER1 ? bias[col] : 0.f;
#pragma unroll
            for (int i = 0; i < 4; ++i) {
                int row = n0 + f * 16 + lg * 4 + i;
                if (row < N_NODES) {
                    float v = acc[f][oc][i] + b;
                    if (LAYER1) {
                        outb[(size_t)row * 128 + col] = bf16_rne(fmaxf(v, 0.f));
                    } else {
                        if (oc < 4) outb[(size_t)row * 64 + col] = bf16_rne(v);
                        else        outf[(size_t)row * 64 + (col - 64)] = v;
                    }
                }
            }
        }
    }
}

// ---------------------------------------------------------------------------
// Launch
// ---------------------------------------------------------------------------
extern "C" void kernel_launch(void* const* d_in, const int* in_sizes, int n_in,
                              void* d_out, int out_size, void* d_ws, size_t ws_size,
                              hipStream_t stream) {
    const int*   ei  = (const int*)d_in[0];
    const float* ue  = (const float*)d_in[1];
    const float* me  = (const float*)d_in[2];
    const float* W1l = (const float*)d_in[3];
    const float* b1  = (const float*)d_in[4];
    const float* W1r = (const float*)d_in[5];
    const float* W2l = (const float*)d_in[6];
    const float* b2  = (const float*)d_in[7];
    const float* W2r = (const float*)d_in[8];
    float* out = (float*)d_out;

    // ws: row_ptr | srclist | ord | wb | xb | h1b (alias wf) | zb  (~85.5 MB)
    char* p = (char*)d_ws;
    int* row_ptr = (int*)p;                   p += (((N_NODES + 1) * 4) + 255) / 256 * 256;
    int* srclist = (int*)p;                   p += (size_t)N_EDGES * 4;
    int* ord     = (int*)p;                   p += (size_t)N_EDGES * 4;
    unsigned short* wb = (unsigned short*)p;  p += 2 * 128 * 128 * 2;
    unsigned short* xb = (unsigned short*)p;  p += (size_t)N_NODES * 64 * 2;
    unsigned short* h1b = (unsigned short*)p; p += (size_t)N_NODES * 128 * 2;
    unsigned short* zb  = (unsigned short*)p; p += (size_t)N_NODES * 64 * 2;
    float* wf = (float*)h1b;                  // byte-exact row alias (see gemm)
    int* cnt  = (int*)h1b;                    // overlay, dead after scan1
    int* bsum = cnt + N_NODES;
    unsigned short* aggb = (unsigned short*)out;   // staged in d_out

    const int NB  = (N_NODES + 1023) / 1024;
    const int EB4 = (N_EDGES / 4 + 255) / 256;

    hipMemsetAsync(cnt, 0, N_NODES * sizeof(int), stream);
    csr_ord<<<EB4, 256, 0, stream>>>(ei, cnt, ord);
    scan1<<<NB, 256, 0, stream>>>(cnt, row_ptr, bsum);
    scan2<<<1, 256, 0, stream>>>(bsum, NB);
    scan3<<<NB, 256, 0, stream>>>(row_ptr, bsum);
    csr_scatter<<<EB4, 256, 0, stream>>>(ei, row_ptr, ord, srclist);
    prepack_w<<<(2 * 128 * 128 + 255) / 256, 256, 0, stream>>>(W1l, W1r, W2l, W2r, wb);
    pack_x<<<(N_NODES * 8 + 255) / 256, 256, 0, stream>>>(ue, me, xb);

    int gblocks = (N_NODES * 8 + 255) / 256;
    int mblocks = (N_NODES + 127) / 128;

    gather1<<<gblocks, 256, 0, stream>>>(row_ptr, srclist, xb, aggb);
    gemm_bf16<true><<<mblocks, 256, 0, stream>>>(aggb, xb, wb, b1, h1b, nullptr);
    gemm_bf16<false><<<mblocks, 256, 0, stream>>>(h1b, nullptr, wb, nullptr, zb, wf);
    gather2_final<<<gblocks, 256, 0, stream>>>(row_ptr, srclist, zb, wf, b2, out);
}

// Round 10
// 177.224 us; speedup vs baseline: 5.0445x; 1.1670x over previous
//
#include <hip/hip_runtime.h>

constexpr int N_USERS  = 100000;
constexpr int N_MOVIES = 50000;
constexpr int N_NODES  = N_USERS + N_MOVIES;   // 150000
constexpr int N_EDGES  = 1000000;

typedef __attribute__((ext_vector_type(8))) short bf16x8;
typedef __attribute__((ext_vector_type(8))) unsigned short usx8;
typedef __attribute__((ext_vector_type(4))) float f32x4;

__device__ inline unsigned short bf16_rne(float x) {
    unsigned u = __float_as_uint(x);
    unsigned r = (u + 0x7FFF + ((u >> 16) & 1)) >> 16;
    return (unsigned short)r;
}
__device__ inline float bf16_to_f(short v) {
    return __uint_as_float(((unsigned)(unsigned short)v) << 16);
}

// grid partition for prep_fused
constexpr int ORD_BLKS = (N_EDGES / 8 + 255) / 256;        // 489 (8 edges/thr)
constexpr int PW_BLKS  = (2 * 128 * 128) / 256;            // 128
constexpr int PX_BLKS  = (N_NODES * 8 + 255) / 256;        // 4688

// ---------------------------------------------------------------------------
// prep_fused: [csr_ord | prepack_w | pack_x] in one launch.
// ord section is atomic-latency bound with idle VALU/HBM; the streaming pack
// sections co-schedule on other CUs/waves and hide under it.
// ---------------------------------------------------------------------------
__global__ __launch_bounds__(256) void prep_fused(const int* __restrict__ ei,
                                                  int* __restrict__ cnt,
                                                  int* __restrict__ ord,
                                                  const float* __restrict__ W1l,
                                                  const float* __restrict__ W1r,
                                                  const float* __restrict__ W2l,
                                                  const float* __restrict__ W2r,
                                                  unsigned short* __restrict__ wb,
                                                  const float* __restrict__ ue,
                                                  const float* __restrict__ me,
                                                  unsigned short* __restrict__ xb) {
    const int ob = blockIdx.x;
    if (ob < ORD_BLKS) {
        // --- csr_ord: 8 edges/thread, ord[e] = within-dst ordinal ---
        int t  = ob * 256 + threadIdx.x;
        int e0 = t * 8;
        if (e0 + 7 < N_EDGES) {
            int4 d0 = *(const int4*)&ei[N_EDGES + e0];
            int4 d1 = *(const int4*)&ei[N_EDGES + e0 + 4];
            int4 o0, o1;
            o0.x = atomicAdd(&cnt[d0.x], 1);
            o0.y = atomicAdd(&cnt[d0.y], 1);
            o0.z = atomicAdd(&cnt[d0.z], 1);
            o0.w = atomicAdd(&cnt[d0.w], 1);
            o1.x = atomicAdd(&cnt[d1.x], 1);
            o1.y = atomicAdd(&cnt[d1.y], 1);
            o1.z = atomicAdd(&cnt[d1.z], 1);
            o1.w = atomicAdd(&cnt[d1.w], 1);
            *(int4*)&ord[e0]     = o0;
            *(int4*)&ord[e0 + 4] = o1;
        } else {
            for (int e = e0; e < N_EDGES; ++e)
                ord[e] = atomicAdd(&cnt[ei[N_EDGES + e]], 1);
        }
        return;
    }
    if (ob < ORD_BLKS + PW_BLKS) {
        // --- prepack_w: weights -> MFMA B-frag order, bf16.
        // i = ((layer*4 + kc)*8 + oc)*512 + lane*8 + j
        //   k = kc*32 + (lane>>4)*8 + j ; o = oc*16 + (lane&15)
        int i = (ob - ORD_BLKS) * 256 + threadIdx.x;
        int layer = i >> 14;
        int r     = i & 16383;
        int kc    = r >> 12;
        int oc    = (r >> 9) & 7;
        int lane  = (r >> 3) & 63;
        int j     = r & 7;
        int k = kc * 32 + (lane >> 4) * 8 + j;
        int o = oc * 16 + (lane & 15);
        float v;
        if (layer == 0) v = (k < 64) ? W1l[o * 64 + k] : W1r[o * 64 + (k - 64)];
        else            v = (o < 64) ? W2l[o * 128 + k] : W2r[(o - 64) * 128 + k];
        wb[i] = bf16_rne(v);
        return;
    }
    // --- pack_x: xb[n][64] bf16 <- concat(ue, me) ---
    int i = (ob - ORD_BLKS - PW_BLKS) * 256 + threadIdx.x;
    if (i >= N_NODES * 8) return;
    int n = i >> 3, c = (i & 7) * 8;
    const float* src = (n < N_USERS) ? &ue[(size_t)n * 64 + c]
                                     : &me[(size_t)(n - N_USERS) * 64 + c];
    float4 v0 = *(const float4*)src;
    float4 v1 = *(const float4*)(src + 4);
    usx8 r;
    r[0] = bf16_rne(v0.x); r[1] = bf16_rne(v0.y);
    r[2] = bf16_rne(v0.z); r[3] = bf16_rne(v0.w);
    r[4] = bf16_rne(v1.x); r[5] = bf16_rne(v1.y);
    r[6] = bf16_rne(v1.z); r[7] = bf16_rne(v1.w);
    *(usx8*)&xb[(size_t)n * 64 + c] = r;
}

// ---------------------------------------------------------------------------
// scan1: per-1024 exclusive scan of cnt into row_ptr + block sums
// ---------------------------------------------------------------------------
__global__ __launch_bounds__(256) void scan1(const int* __restrict__ cnt,
                                             int* __restrict__ part,
                                             int* __restrict__ bsum) {
    __shared__ int sh[256];
    int t = threadIdx.x, b = blockIdx.x;
    int base = b * 1024 + t * 4;
    int v[4]; int s = 0;
#pragma unroll
    for (int j = 0; j < 4; ++j) {
        int i = base + j;
        v[j] = (i < N_NODES) ? cnt[i] : 0;
        s += v[j];
    }
    sh[t] = s; __syncthreads();
    for (int off = 1; off < 256; off <<= 1) {
        int x = (t >= off) ? sh[t - off] : 0;
        __syncthreads();
        sh[t] += x;
        __syncthreads();
    }
    int run = sh[t] - s;
#pragma unroll
    for (int j = 0; j < 4; ++j) {
        int i = base + j;
        if (i < N_NODES) part[i] = run;
        run += v[j];
    }
    if (t == 255) bsum[b] = sh[255];
}

// ---------------------------------------------------------------------------
// scan23: merged — every block re-scans bsum (nb<=256) locally, adds prefix.
// ---------------------------------------------------------------------------
__global__ __launch_bounds__(256) void scan23(int* __restrict__ row_ptr,
                                              const int* __restrict__ bsum,
                                              int nb) {
    __shared__ int sh[256];
    int t = threadIdx.x, b = blockIdx.x;
    int v = (t < nb) ? bsum[t] : 0;
    sh[t] = v; __syncthreads();
    for (int off = 1; off < 256; off <<= 1) {
        int x = (t >= off) ? sh[t - off] : 0;
        __syncthreads();
        sh[t] += x;
        __syncthreads();
    }
    int add = (b == 0) ? 0 : sh[b - 1];
    int base = b * 1024 + t * 4;
#pragma unroll
    for (int j = 0; j < 4; ++j) {
        int i = base + j;
        if (i < N_NODES) row_ptr[i] += add;
    }
    if (b == 0 && t == 0) row_ptr[N_NODES] = N_EDGES;
}

// ---------------------------------------------------------------------------
// csr_scatter: no atomics; srclist[row_ptr[dst]+ord[e]] = src
// ---------------------------------------------------------------------------
__global__ __launch_bounds__(256) void csr_scatter(const int* __restrict__ ei,
                                                   const int* __restrict__ row_ptr,
                                                   const int* __restrict__ ord,
                                                   int* __restrict__ srclist) {
    int t  = blockIdx.x * 256 + threadIdx.x;
    int e0 = t * 4;
    if (e0 + 3 < N_EDGES) {
        int4 s = *(const int4*)&ei[e0];
        int4 d = *(const int4*)&ei[N_EDGES + e0];
        int4 o = *(const int4*)&ord[e0];
        srclist[row_ptr[d.x] + o.x] = s.x;
        srclist[row_ptr[d.y] + o.y] = s.y;
        srclist[row_ptr[d.z] + o.z] = s.z;
        srclist[row_ptr[d.w] + o.w] = s.w;
    } else {
        for (int e = e0; e < N_EDGES; ++e)
            srclist[row_ptr[ei[N_EDGES + e]] + ord[e]] = ei[e];
    }
}

// ---------------------------------------------------------------------------
// gather1: 8 lanes/node (16B row slice each), 8 nodes/wave, no reduction.
// ---------------------------------------------------------------------------
__global__ __launch_bounds__(256) void gather1(const int* __restrict__ row_ptr,
                                               const int* __restrict__ srclist,
                                               const unsigned short* __restrict__ xb,
                                               unsigned short* __restrict__ aggb) {
    int gid = blockIdx.x * 256 + threadIdx.x;
    int n = gid >> 3, l = gid & 7;
    if (n >= N_NODES) return;
    int s0 = row_ptr[n], s1 = row_ptr[n + 1];
    float acc[8] = {};
    for (int i = s0; i < s1; ++i) {
        int a = srclist[i];
        bf16x8 v = *(const bf16x8*)&xb[(size_t)a * 64 + l * 8];
#pragma unroll
        for (int j = 0; j < 8; ++j) acc[j] += bf16_to_f(v[j]);
    }
    float inv = 1.0f / fmaxf((float)(s1 - s0), 1.0f);
    usx8 r;
#pragma unroll
    for (int j = 0; j < 8; ++j) r[j] = bf16_rne(acc[j] * inv);
    *(usx8*)&aggb[(size_t)n * 64 + l * 8] = r;
}

// ---------------------------------------------------------------------------
// gather2+final: out[n][:] = mean_nbrs(zb[src]) + wfb[n] + b2   (wfb bf16)
// ---------------------------------------------------------------------------
__global__ __launch_bounds__(256) void gather2_final(const int* __restrict__ row_ptr,
                                                     const int* __restrict__ srclist,
                                                     const unsigned short* __restrict__ zb,
                                                     const unsigned short* __restrict__ wfb,
                                                     const float* __restrict__ b2,
                                                     float* __restrict__ out) {
    int gid = blockIdx.x * 256 + threadIdx.x;
    int n = gid >> 3, l = gid & 7;
    if (n >= N_NODES) return;
    int s0 = row_ptr[n], s1 = row_ptr[n + 1];
    float acc[8] = {};
    for (int i = s0; i < s1; ++i) {
        int a = srclist[i];
        bf16x8 v = *(const bf16x8*)&zb[(size_t)a * 64 + l * 8];
#pragma unroll
        for (int j = 0; j < 8; ++j) acc[j] += bf16_to_f(v[j]);
    }
    float inv = 1.0f / fmaxf((float)(s1 - s0), 1.0f);
    bf16x8 wv = *(const bf16x8*)&wfb[(size_t)n * 64 + l * 8];
    float4 c0 = *(const float4*)&b2[l * 8];
    float4 c1 = *(const float4*)&b2[l * 8 + 4];
    float4 r0, r1;
    r0.x = acc[0] * inv + bf16_to_f(wv[0]) + c0.x;
    r0.y = acc[1] * inv + bf16_to_f(wv[1]) + c0.y;
    r0.z = acc[2] * inv + bf16_to_f(wv[2]) + c0.z;
    r0.w = acc[3] * inv + bf16_to_f(wv[3]) + c0.w;
    r1.x = acc[4] * inv + bf16_to_f(wv[4]) + c1.x;
    r1.y = acc[5] * inv + bf16_to_f(wv[5]) + c1.y;
    r1.z = acc[6] * inv + bf16_to_f(wv[6]) + c1.z;
    r1.w = acc[7] * inv + bf16_to_f(wv[7]) + c1.w;
    *(float4*)&out[(size_t)n * 64 + l * 8]     = r0;
    *(float4*)&out[(size_t)n * 64 + l * 8 + 4] = r1;
}

// ---------------------------------------------------------------------------
// gemm_fused: layer1 + layer2 in one kernel, h1 tile staged in LDS.
// Block = 128 nodes, 4 waves; wave owns rows [w*32, w*32+32).
// L1: acc1 = [aggb|xb] @ W1cat (MFMA, A global->reg); epilogue writes
//     h1 = relu(acc1+b1) as bf16 into hs[128][136] (pad 8 -> <=2-way banks).
// barrier.
// L2: A-frags from LDS (ds_read_b128, row=lane&15 matches A layout);
//     out: zb bf16 [n][64] (oc<4), wfb bf16 [n][64] (oc>=4).
// D frag: col=lane&15, row=(lane>>4)*4+reg (m89-verified mapping).
// ---------------------------------------------------------------------------
__global__ __launch_bounds__(256) void gemm_fused(const unsigned short* __restrict__ aggb,
                                                  const unsigned short* __restrict__ xb,
                                                  const unsigned short* __restrict__ wb,
                                                  const float* __restrict__ b1,
                                                  unsigned short* __restrict__ zb,
                                                  unsigned short* __restrict__ wfb) {
    __shared__ unsigned short hs[128][136];
    const int tid  = threadIdx.x;
    const int w    = tid >> 6;
    const int lane = tid & 63;
    const int n0   = blockIdx.x * 128;
    const int nw   = n0 + w * 32;
    const int lr   = lane & 15;
    const int lg   = lane >> 4;

    // ---- layer 1 ----
    {
        f32x4 acc[2][8] = {};
        for (int kc = 0; kc < 4; ++kc) {
            const int k0 = kc * 32 + lg * 8;
            bf16x8 a[2];
#pragma unroll
            for (int f = 0; f < 2; ++f) {
                int node = nw + f * 16 + lr;
                bf16x8 z = {};
                a[f] = z;
                if (node < N_NODES) {
                    const unsigned short* ap = (k0 < 64)
                        ? &aggb[(size_t)node * 64 + k0]
                        : &xb[(size_t)node * 64 + (k0 - 64)];
                    a[f] = *(const bf16x8*)ap;
                }
            }
#pragma unroll
            for (int oc = 0; oc < 8; ++oc) {
                size_t widx = ((size_t)((kc * 8 + oc) * 64 + lane)) * 8;
                bf16x8 wfrag = *(const bf16x8*)&wb[widx];
#pragma unroll
                for (int f = 0; f < 2; ++f)
                    acc[f][oc] = __builtin_amdgcn_mfma_f32_16x16x32_bf16(a[f], wfrag, acc[f][oc], 0, 0, 0);
            }
        }
        // epilogue 1 -> LDS (bf16, relu)
#pragma unroll
        for (int f = 0; f < 2; ++f) {
#pragma unroll
            for (int oc = 0; oc < 8; ++oc) {
                int col = oc * 16 + lr;
                float b = b1[col];
#pragma unroll
                for (int i = 0; i < 4; ++i) {
                    int rowl = w * 32 + f * 16 + lg * 4 + i;
                    hs[rowl][col] = bf16_rne(fmaxf(acc[f][oc][i] + b, 0.f));
                }
            }
        }
    }
    __syncthreads();

    // ---- layer 2 ----
    {
        f32x4 acc[2][8] = {};
        for (int kc = 0; kc < 4; ++kc) {
            const int k0 = kc * 32 + lg * 8;
            bf16x8 a[2];
#pragma unroll
            for (int f = 0; f < 2; ++f) {
                int rowl = w * 32 + f * 16 + lr;
                a[f] = *(const bf16x8*)&hs[rowl][k0];
            }
#pragma unroll
            for (int oc = 0; oc < 8; ++oc) {
                size_t widx = ((size_t)(2048 + (kc * 8 + oc) * 64 + lane)) * 8;
                bf16x8 wfrag = *(const bf16x8*)&wb[widx];
#pragma unroll
                for (int f = 0; f < 2; ++f)
                    acc[f][oc] = __builtin_amdgcn_mfma_f32_16x16x32_bf16(a[f], wfrag, acc[f][oc], 0, 0, 0);
            }
        }
        // epilogue 2 -> zb / wfb
#pragma unroll
        for (int f = 0; f < 2; ++f) {
#pragma unroll
            for (int oc = 0; oc < 8; ++oc) {
                int col = oc * 16 + lr;
#pragma unroll
                for (int i = 0; i < 4; ++i) {
                    int row = nw + f * 16 + lg * 4 + i;
                    if (row < N_NODES) {
                        unsigned short v = bf16_rne(acc[f][oc][i]);
                        if (oc < 4) zb[(size_t)row * 64 + col] = v;
                        else        wfb[(size_t)row * 64 + (col - 64)] = v;
                    }
                }
            }
        }
    }
}

// ---------------------------------------------------------------------------
// Launch
// ---------------------------------------------------------------------------
extern "C" void kernel_launch(void* const* d_in, const int* in_sizes, int n_in,
                              void* d_out, int out_size, void* d_ws, size_t ws_size,
                              hipStream_t stream) {
    const int*   ei  = (const int*)d_in[0];
    const float* ue  = (const float*)d_in[1];
    const float* me  = (const float*)d_in[2];
    const float* W1l = (const float*)d_in[3];
    const float* b1  = (const float*)d_in[4];
    const float* W1r = (const float*)d_in[5];
    const float* W2l = (const float*)d_in[6];
    const float* b2  = (const float*)d_in[7];
    const float* W2r = (const float*)d_in[8];
    float* out = (float*)d_out;

    // ws: row_ptr | srclist | ord | wb | xb | zb | wfb   (~66.5 MB)
    char* p = (char*)d_ws;
    int* row_ptr = (int*)p;                   p += (((N_NODES + 1) * 4) + 255) / 256 * 256;
    int* srclist = (int*)p;                   p += (size_t)N_EDGES * 4;
    int* ord     = (int*)p;                   p += (size_t)N_EDGES * 4;
    unsigned short* wb  = (unsigned short*)p; p += 2 * 128 * 128 * 2;
    unsigned short* xb  = (unsigned short*)p; p += (size_t)N_NODES * 64 * 2;
    unsigned short* zb  = (unsigned short*)p; p += (size_t)N_NODES * 64 * 2;
    unsigned short* wfb = (unsigned short*)p; p += (size_t)N_NODES * 64 * 2;
    int* cnt  = (int*)zb;                     // overlay: dead until gemm_fused
    int* bsum = cnt + N_NODES;                // (zb region is 19.2MB > 601KB)
    unsigned short* aggb = (unsigned short*)out;   // staged in d_out

    const int NB = (N_NODES + 1023) / 1024;   // 147

    hipMemsetAsync(cnt, 0, N_NODES * sizeof(int), stream);
    prep_fused<<<ORD_BLKS + PW_BLKS + PX_BLKS, 256, 0, stream>>>(
        ei, cnt, ord, W1l, W1r, W2l, W2r, wb, ue, me, xb);
    scan1<<<NB, 256, 0, stream>>>(cnt, row_ptr, bsum);
    scan23<<<NB, 256, 0, stream>>>(row_ptr, bsum, NB);
    csr_scatter<<<(N_EDGES / 4 + 255) / 256, 256, 0, stream>>>(ei, row_ptr, ord, srclist);

    int gblocks = (N_NODES * 8 + 255) / 256;
    int mblocks = (N_NODES + 127) / 128;

    gather1<<<gblocks, 256, 0, stream>>>(row_ptr, srclist, xb, aggb);
    gemm_fused<<<mblocks, 256, 0, stream>>>(aggb, xb, wb, b1, zb, wfb);
    gather2_final<<<gblocks, 256, 0, stream>>>(row_ptr, srclist, zb, wfb, b2, out);
}